// Round 4
// baseline (1851.446 us; speedup 1.0000x reference)
//
#include <hip/hip_runtime.h>

#define NTOT 12288
#define MAXDEG 64

typedef __attribute__((ext_vector_type(8))) short bf8_t;   // 8 bf16 (4 VGPRs)
typedef __attribute__((ext_vector_type(4))) float f32x4;   // MFMA C/D frag

// turn-local row r (0..2047) of turn t -> global node id
__device__ __forceinline__ int turn_row_map(int r, int t) {
  return (r >> 7) * 768 + t * 128 + (r & 127);
}

// split fp32 into bf16 hi (truncate) + bf16 lo (truncated residual): ~2^-16 rel
__device__ __forceinline__ void splitbf(float x, unsigned short& hi, unsigned short& lo) {
  unsigned u = __float_as_uint(x);
  hi = (unsigned short)(u >> 16);
  float fh = __uint_as_float(u & 0xFFFF0000u);
  lo = (unsigned short)(__float_as_uint(x - fh) >> 16);
}
__device__ __forceinline__ float reconf(unsigned short hi, unsigned short lo) {
  return __uint_as_float((unsigned)hi << 16) + __uint_as_float((unsigned)lo << 16);
}
__device__ __forceinline__ uint2 pack4(unsigned short a, unsigned short b,
                                       unsigned short c, unsigned short d) {
  return make_uint2((unsigned)a | ((unsigned)b << 16), (unsigned)c | ((unsigned)d << 16));
}

// inter-block release/acquire (device-scope): producer signal / consumer wait
__device__ __forceinline__ void block_signal(int* f) {
  __syncthreads();        // all block stores issued
  __threadfence();        // release to device scope
  if (threadIdx.x == 0) atomicAdd(f, 1);
}
__device__ __forceinline__ void block_wait(int* f, int target) {
  if (threadIdx.x == 0)
    while (atomicAdd(f, 0) < target) __builtin_amdgcn_s_sleep(1);
  __syncthreads();
  __threadfence();        // acquire side
}

// shared 32x64-tile split-bf16 GEMM core, K=256, LDS-staged BK=64 (R1-proven)
__device__ __forceinline__ void gemm32x64(
    const unsigned short* __restrict__ ahp, const unsigned short* __restrict__ alp,
    const unsigned short* __restrict__ bhp, const unsigned short* __restrict__ blp,
    unsigned short (&Ah)[32][72], unsigned short (&Al)[32][72],
    unsigned short (&Bh)[64][72], unsigned short (&Bl)[64][72],
    int ar, int aq, int bn_, int bq, int rh, int ch, int quad, int nl,
    f32x4& acc0, f32x4& acc1) {
  for (int k0 = 0; k0 < 256; k0 += 64) {
    *(uint4*)&Ah[ar][aq * 8] = *(const uint4*)(ahp + k0 + aq * 8);
    *(uint4*)&Al[ar][aq * 8] = *(const uint4*)(alp + k0 + aq * 8);
    *(uint4*)&Bh[bn_][bq * 16]     = *(const uint4*)(bhp + k0 + bq * 16);
    *(uint4*)&Bh[bn_][bq * 16 + 8] = *(const uint4*)(bhp + k0 + bq * 16 + 8);
    *(uint4*)&Bl[bn_][bq * 16]     = *(const uint4*)(blp + k0 + bq * 16);
    *(uint4*)&Bl[bn_][bq * 16 + 8] = *(const uint4*)(blp + k0 + bq * 16 + 8);
    __syncthreads();
#pragma unroll
    for (int kk = 0; kk < 64; kk += 32) {
      bf8_t a_h = *(const bf8_t*)&Ah[rh * 16 + nl][kk + quad * 8];
      bf8_t a_l = *(const bf8_t*)&Al[rh * 16 + nl][kk + quad * 8];
      bf8_t bh0 = *(const bf8_t*)&Bh[ch * 32 + nl][kk + quad * 8];
      bf8_t bl0 = *(const bf8_t*)&Bl[ch * 32 + nl][kk + quad * 8];
      bf8_t bh1 = *(const bf8_t*)&Bh[ch * 32 + 16 + nl][kk + quad * 8];
      bf8_t bl1 = *(const bf8_t*)&Bl[ch * 32 + 16 + nl][kk + quad * 8];
      acc0 = __builtin_amdgcn_mfma_f32_16x16x32_bf16(a_h, bh0, acc0, 0, 0, 0);
      acc1 = __builtin_amdgcn_mfma_f32_16x16x32_bf16(a_h, bh1, acc1, 0, 0, 0);
      acc0 = __builtin_amdgcn_mfma_f32_16x16x32_bf16(a_h, bl0, acc0, 0, 0, 0);
      acc1 = __builtin_amdgcn_mfma_f32_16x16x32_bf16(a_h, bl1, acc1, 0, 0, 0);
      acc0 = __builtin_amdgcn_mfma_f32_16x16x32_bf16(a_l, bh0, acc0, 0, 0, 0);
      acc1 = __builtin_amdgcn_mfma_f32_16x16x32_bf16(a_l, bh1, acc1, 0, 0, 0);
    }
    __syncthreads();
  }
}

// ---------------- fused prologue: feat | wconv (LDS transpose) | adj ----------------
__global__ void __launch_bounds__(256)
k_prep(const float* __restrict__ emb, const float* __restrict__ nmask,
       const int* __restrict__ nodeidx,
       const float* __restrict__ W, const float* __restrict__ Wz,
       const float* __restrict__ Wr, const float* __restrict__ Wn,
       const float* __restrict__ Uz, const float* __restrict__ Ur,
       const float* __restrict__ Un,
       const int* __restrict__ esrc, const int* __restrict__ edst, int* __restrict__ cnt,
       unsigned short* __restrict__ hbh, unsigned short* __restrict__ hbl,
       unsigned short* __restrict__ wth, unsigned short* __restrict__ wtl,
       unsigned short* __restrict__ adj) {
  int l = blockIdx.x, tid = threadIdx.x;
  if (l < 3072) {            // feat: NTOT*64 float4 -> bf planes only
    int i = l * 256 + tid;
    int row = i >> 6;
    int src = nodeidx[row];
    float m = nmask[src];
    float4 v = ((const float4*)emb)[(size_t)src * 64 + (i & 63)];
    v.x *= m; v.y *= m; v.z *= m; v.w *= m;
    unsigned short h0,l0,h1,l1,h2,l2,h3,l3;
    splitbf(v.x,h0,l0); splitbf(v.y,h1,l1); splitbf(v.z,h2,l2); splitbf(v.w,h3,l3);
    int o = row * 256 + (i & 63) * 4;
    *(uint2*)(hbh + o) = pack4(h0,h1,h2,h3);
    *(uint2*)(hbl + o) = pack4(l0,l1,l2,l3);
  } else if (l < 3184) {     // wconv: 112 blocks = 7 matrices x 16 (64x64) tiles
    __shared__ float ldt[64][65];
    int bidx = l - 3072;
    int g = bidx >> 4, ti = bidx & 15;
    int tk = (ti & 3) * 64, tn = (ti >> 2) * 64;
    const float* M = g==0?W : g==1?Wz : g==2?Wr : g==3?Wn : g==4?Uz : g==5?Ur : Un;
#pragma unroll
    for (int p = 0; p < 16; p++) {
      int r = p * 4 + (tid >> 6);            // k-local row
      ldt[r][tid & 63] = M[(size_t)(tk + r) * 256 + tn + (tid & 63)];  // coalesced
    }
    __syncthreads();
#pragma unroll
    for (int p = 0; p < 16; p++) {
      int nl_ = p * 4 + (tid >> 6);          // n-local
      int kl = tid & 63;                     // k-local
      float v = ldt[kl][nl_];
      unsigned short hh, ll; splitbf(v, hh, ll);
      int idx = (g * 256 + tn + nl_) * 256 + tk + kl;   // wth[n][k], coalesced in k
      wth[idx] = hh; wtl[idx] = ll;
    }
  } else {                   // adj
    int e = (l - 3184) * 256 + tid;
    int d = edst[e];
    int pos = atomicAdd(&cnt[d], 1);
    if (pos < MAXDEG) adj[(size_t)d * MAXDEG + pos] = (unsigned short)esrc[e];
  }
}

// -------- bulk GEMM: Wh/es/ed all nodes + uacc banks, 32x64 tile, LDS-staged BK=64 ----
__global__ void __launch_bounds__(256)
k_mf5(const unsigned short* __restrict__ aph, const unsigned short* __restrict__ apl,
      const unsigned short* __restrict__ wth, const unsigned short* __restrict__ wtl,
      float* __restrict__ Wh, float* __restrict__ uacc,
      const float* __restrict__ bz, const float* __restrict__ br,
      const float* __restrict__ asrc, const float* __restrict__ adst,
      float* __restrict__ es, float* __restrict__ ed) {
  __shared__ __align__(16) unsigned short Ah[32][72], Al[32][72];
  __shared__ __align__(16) unsigned short Bh[64][72], Bl[64][72];
  __shared__ float esb[32][2], edb[32][2];
  int l = blockIdx.x, tid = threadIdx.x;
  int q = (l < 1536) ? 0 : (l < 3072 ? 1 : 2);
  int bx, by;
  if (q == 0) { bx = (l & 31) >> 3; by = (l >> 5) * 8 + (l & 7); }                 // 4 x 384
  else { int l2 = l - (q == 1 ? 1536 : 3072); bx = (l2 & 63) >> 3; by = (l2 >> 6) * 8 + (l2 & 7); }  // 8 x 192

  int ar = tid >> 3, aq = tid & 7;
  int bn_ = tid >> 2, bq = tid & 3;
  int gmA = by * 32 + ar;
  int arow;
  if (q == 0) arow = gmA;
  else arow = (gmA / 384) * 768 + (((q == 2) ? 3 : 0) + ((gmA % 384) >> 7)) * 128 + (gmA & 127);
  const unsigned short* ahp = aph + (size_t)arow * 256;
  const unsigned short* alp = apl + (size_t)arow * 256;
  int nbase = (q == 0) ? bx * 64 : 1024 + bx * 64;
  const unsigned short* bhp = wth + (size_t)(nbase + bn_) * 256;
  const unsigned short* blp = wtl + (size_t)(nbase + bn_) * 256;

  int lane = tid & 63, wv = tid >> 6;
  int rh = wv >> 1, ch = wv & 1;
  int quad = lane >> 4, nl = lane & 15;
  f32x4 acc0 = {0.f, 0.f, 0.f, 0.f}, acc1 = {0.f, 0.f, 0.f, 0.f};
  gemm32x64(ahp, alp, bhp, blp, Ah, Al, Bh, Bl, ar, aq, bn_, bq, rh, ch, quad, nl, acc0, acc1);

  int gr = by * 32 + rh * 16 + quad * 4;
  if (q != 0) {  // uacc epilogue (bank0 rows [0,6144), bank1 [6144,12288))
    int rbase = (q == 2) ? 6144 : 0;
#pragma unroll
    for (int r = 0; r < 4; r++) {
      int grr = gr + r;
#pragma unroll
      for (int ct = 0; ct < 2; ct++) {
        float D = (ct == 0) ? acc0[r] : acc1[r];
        int col = bx * 64 + ch * 32 + ct * 16 + nl;
        float bias = (col < 256) ? bz[col] : br[col - 256];
        uacc[(size_t)(rbase + grr) * 512 + col] = D + bias;
      }
    }
  } else {  // Wh + es/ed epilogue
    int c0 = bx * 64 + ch * 32 + nl, c1 = c0 + 16;
    float a0 = asrc[c0], a1 = asrc[c1], d0 = adst[c0], d1 = adst[c1];
    float pes[4], ped[4];
#pragma unroll
    for (int r = 0; r < 4; r++) {
      int v = gr + r;
      float x0 = acc0[r], x1 = acc1[r];
      Wh[(size_t)v * 256 + c0] = x0;
      Wh[(size_t)v * 256 + c1] = x1;
      pes[r] = x0 * a0 + x1 * a1;
      ped[r] = x0 * d0 + x1 * d1;
    }
#pragma unroll
    for (int m = 1; m < 16; m <<= 1)
#pragma unroll
      for (int r = 0; r < 4; r++) {
        pes[r] += __shfl_xor(pes[r], m);
        ped[r] += __shfl_xor(ped[r], m);
      }
    if (nl == 0)
#pragma unroll
      for (int r = 0; r < 4; r++) {
        esb[rh * 16 + quad * 4 + r][ch] = pes[r];
        edb[rh * 16 + quad * 4 + r][ch] = ped[r];
      }
    __syncthreads();
    if (tid < 32) {
      int m = tid;
      int v = by * 32 + m;
      es[v * 4 + bx] = esb[m][0] + esb[m][1];
      ed[v * 4 + bx] = edb[m][0] + edb[m][1];
    }
  }
}

// -------- whole turn in ONE dispatch (768 blocks), flag-chained phases --------
// ph0 attn (blocks 0..511, 4 dst/block) -> ph1 gates mf2 (all, gated on 8 msg flags)
// -> ph2 GRU mf3 (blocks 512..767, gated on 12 mf2 flags) -> ph3 upd (same, gated on
// 4 h flags + all-attn-done).  All 768 blocks co-resident (LDS 32KB, VGPR<=128).
__global__ void __launch_bounds__(256, 4)
k_turn(const int* __restrict__ cnt, const unsigned short* __restrict__ adj,
       float* __restrict__ es, float* __restrict__ ed, float* __restrict__ Wh,
       const unsigned short* __restrict__ wth, const unsigned short* __restrict__ wtl,
       unsigned short* __restrict__ mbh, unsigned short* __restrict__ mbl,
       unsigned short* __restrict__ rbh, unsigned short* __restrict__ rbl,
       float* __restrict__ g1, const float* __restrict__ uacc,
       const float* __restrict__ bn,
       unsigned short* __restrict__ hbh, unsigned short* __restrict__ hbl,
       const float* __restrict__ asrc, const float* __restrict__ adst,
       int* __restrict__ flags, float* __restrict__ outp, int t) {
  __shared__ __align__(16) unsigned short Ah[32][72], Al[32][72];
  __shared__ __align__(16) unsigned short Bh[64][72], Bl[64][72];
  __shared__ float esb[32][2], edb[32][2];
  __shared__ float wgs[4][64][4];
  __shared__ unsigned short ssrc[4][64];
  int b = blockIdx.x, tid = threadIdx.x;
  int lane = tid & 63, wv = tid >> 6;
  int quad = lane >> 4, nl = lane & 15;
  int rh = wv >> 1, ch = wv & 1;
  int ar = tid >> 3, aq = tid & 7;
  int bn_ = tid >> 2, bq = tid & 3;
  int* msgf = flags + t * 64;
  int* g1f  = flags + 384 + t * 64;
  int* hf   = flags + 768 + t * 64;
  int* d0   = flags + 1152 + t;

  // ---------------- phase 0: attention (blocks 0..511) ----------------
  if (b < 512) {
    int w = b * 4 + wv;
    int v = turn_row_map(w, t);
    int deg = cnt[v]; if (deg > MAXDEG) deg = MAXDEG;
    const unsigned short* row = adj + (size_t)v * MAXDEG;
    float edq = ed[v * 4 + (lane & 3)];
    float dsum = 0.f;
    int passes = (deg + 15) >> 4;
    for (int p = 0; p < passes; p++) {
      int jj = p * 16 + (lane >> 2);
      if (jj < deg) {
        int s = row[jj];
        float lg = es[s * 4 + (lane & 3)] + edq;
        lg = lg >= 0.f ? lg : 0.2f * lg;
        float wgv = __expf(lg);
        wgs[wv][jj][lane & 3] = wgv;
        if ((lane & 3) == 0) ssrc[wv][jj] = (unsigned short)s;
        dsum += wgv;
      } else {
        wgs[wv][jj][lane & 3] = 0.f;
        if ((lane & 3) == 0) ssrc[wv][jj] = 0;
      }
    }
    dsum += __shfl_xor(dsum, 4);
    dsum += __shfl_xor(dsum, 8);
    dsum += __shfl_xor(dsum, 16);
    dsum += __shfl_xor(dsum, 32);
    float invq = 1.f / (dsum + 1e-9f);
    float myinv = __shfl(invq, lane >> 4);  // lanes 0..3 hold heads 0..3
    float4 acc = make_float4(0.f, 0.f, 0.f, 0.f);
    int deg4 = (deg + 3) & ~3;
    for (int j0 = 0; j0 < deg4; j0 += 4) {
#pragma unroll
      for (int u = 0; u < 4; u++) {
        int s = ssrc[wv][j0 + u];
        float wgv = wgs[wv][j0 + u][lane >> 4];
        float4 x = ((const float4*)Wh)[(size_t)s * 64 + lane];
        acc.x += wgv * x.x; acc.y += wgv * x.y;
        acc.z += wgv * x.z; acc.w += wgv * x.w;
      }
    }
    unsigned short h0,l0,h1,l1,h2,l2,h3,l3;
    splitbf(acc.x * myinv, h0, l0); splitbf(acc.y * myinv, h1, l1);
    splitbf(acc.z * myinv, h2, l2); splitbf(acc.w * myinv, h3, l3);
    int o = w * 256 + lane * 4;
    *(uint2*)(mbh + o) = pack4(h0, h1, h2, h3);
    *(uint2*)(mbl + o) = pack4(l0, l1, l2, l3);
    __syncthreads();
    __threadfence();
    if (tid == 0) { atomicAdd(&msgf[b >> 3], 1); atomicAdd(d0, 1); }
  } else if (t == 5 && b < 520) {
    // out-zero for the fused pool epilogue (idle ph0 slot at t=5)
    ((float4*)outp)[(b - 512) * 256 + tid] = make_float4(0.f, 0.f, 0.f, 0.f);
  }

  // ---------------- phase 1: gates mf2 (all 768 blocks) ----------------
  {
    int bx = (b % 96) >> 3, by = (b / 96) * 8 + (b & 7);   // 12 x 64
    block_wait(&msgf[by], 8);
    int gmA = by * 32 + ar;
    const unsigned short* ahp = mbh + (size_t)gmA * 256;
    const unsigned short* alp = mbl + (size_t)gmA * 256;
    int nbase = 256 + bx * 64;
    const unsigned short* bhp = wth + (size_t)(nbase + bn_) * 256;
    const unsigned short* blp = wtl + (size_t)(nbase + bn_) * 256;
    f32x4 acc0 = {0.f, 0.f, 0.f, 0.f}, acc1 = {0.f, 0.f, 0.f, 0.f};
    gemm32x64(ahp, alp, bhp, blp, Ah, Al, Bh, Bl, ar, aq, bn_, bq, rh, ch, quad, nl, acc0, acc1);

    int gr = by * 32 + rh * 16 + quad * 4;
    int g = bx >> 2;
    int tm3 = t % 3;
    const float* up = uacc + (size_t)(t >= 3 ? 6144 : 0) * 512;
#pragma unroll
    for (int r = 0; r < 4; r++) {
      int grr = gr + r;
      int v = turn_row_map(grr, t);
      int urow = (grr >> 7) * 384 + tm3 * 128 + (grr & 127);
#pragma unroll
      for (int ct = 0; ct < 2; ct++) {
        float D = (ct == 0) ? acc0[r] : acc1[r];
        int c = (bx & 3) * 64 + ch * 32 + ct * 16 + nl;
        if (g == 0) {
          g1[(size_t)grr * 512 + c] = D + up[(size_t)urow * 512 + c];
        } else if (g == 1) {
          float rpre = D + up[(size_t)urow * 512 + 256 + c];
          float rv = 1.f / (1.f + __expf(-rpre));
          int hidx = v * 256 + c;
          float hv = reconf(hbh[hidx], hbl[hidx]);
          float rhv = rv * hv;
          unsigned short hh, ll; splitbf(rhv, hh, ll);
          rbh[grr * 256 + c] = hh; rbl[grr * 256 + c] = ll;
        } else {
          g1[(size_t)grr * 512 + 256 + c] = D + bn[c];
        }
      }
    }
    block_signal(&g1f[by]);
  }

  if (b < 512) return;
  int b2 = b - 512;
  int by = b2 & 63, bx = b2 >> 6;   // 64 row-groups x 4 col-tiles

  // ---------------- phase 2: GRU mf3 (blocks 512..767) ----------------
  {
    block_wait(&g1f[by], 12);
    int gmA = by * 32 + ar;
    const unsigned short* ahp = rbh + (size_t)gmA * 256;
    const unsigned short* alp = rbl + (size_t)gmA * 256;
    int nbase = 1536 + bx * 64;              // Un
    const unsigned short* bhp = wth + (size_t)(nbase + bn_) * 256;
    const unsigned short* blp = wtl + (size_t)(nbase + bn_) * 256;
    f32x4 acc0 = {0.f, 0.f, 0.f, 0.f}, acc1 = {0.f, 0.f, 0.f, 0.f};
    gemm32x64(ahp, alp, bhp, blp, Ah, Al, Bh, Bl, ar, aq, bn_, bq, rh, ch, quad, nl, acc0, acc1);

    int gr = by * 32 + rh * 16 + quad * 4;
#pragma unroll
    for (int r = 0; r < 4; r++) {
      int grr = gr + r;
      int v = turn_row_map(grr, t);
#pragma unroll
      for (int ct = 0; ct < 2; ct++) {
        float D = (ct == 0) ? acc0[r] : acc1[r];
        int c = bx * 64 + ch * 32 + ct * 16 + nl;
        float zpre = g1[(size_t)grr * 512 + c];
        float npre = g1[(size_t)grr * 512 + 256 + c] + D;
        float z = 1.f / (1.f + __expf(-zpre));
        float n = tanhf(npre);
        int hidx = v * 256 + c;
        float hv = reconf(hbh[hidx], hbl[hidx]);
        float hn = (1.f - z) * hv + z * n;
        unsigned short hh, ll; splitbf(hn, hh, ll);
        hbh[hidx] = hh;
        hbl[hidx] = ll;
      }
    }
    block_signal(&hf[by]);
  }

  if (t == 5) return;

  // ---------------- phase 3: Wh/es/ed refresh (blocks 512..767) ----------------
  {
    if (tid == 0)
      while (atomicAdd(&hf[by], 0) < 4 || atomicAdd(d0, 0) < 512)
        __builtin_amdgcn_s_sleep(1);
    __syncthreads();
    __threadfence();
    int gmA = by * 32 + ar;
    int arow = turn_row_map(gmA, t);
    const unsigned short* ahp = hbh + (size_t)arow * 256;
    const unsigned short* alp = hbl + (size_t)arow * 256;
    int nbase = bx * 64;                     // W
    const unsigned short* bhp = wth + (size_t)(nbase + bn_) * 256;
    const unsigned short* blp = wtl + (size_t)(nbase + bn_) * 256;
    f32x4 acc0 = {0.f, 0.f, 0.f, 0.f}, acc1 = {0.f, 0.f, 0.f, 0.f};
    gemm32x64(ahp, alp, bhp, blp, Ah, Al, Bh, Bl, ar, aq, bn_, bq, rh, ch, quad, nl, acc0, acc1);

    int gr = by * 32 + rh * 16 + quad * 4;
    int c0 = bx * 64 + ch * 32 + nl, c1 = c0 + 16;
    float a0 = asrc[c0], a1 = asrc[c1], d0v = adst[c0], d1v = adst[c1];
    float pes[4], ped[4];
#pragma unroll
    for (int r = 0; r < 4; r++) {
      int v = turn_row_map(gr + r, t);
      float x0 = acc0[r], x1 = acc1[r];
      Wh[(size_t)v * 256 + c0] = x0;
      Wh[(size_t)v * 256 + c1] = x1;
      pes[r] = x0 * a0 + x1 * a1;
      ped[r] = x0 * d0v + x1 * d1v;
    }
#pragma unroll
    for (int m = 1; m < 16; m <<= 1)
#pragma unroll
      for (int r = 0; r < 4; r++) {
        pes[r] += __shfl_xor(pes[r], m);
        ped[r] += __shfl_xor(ped[r], m);
      }
    if (nl == 0)
#pragma unroll
      for (int r = 0; r < 4; r++) {
        esb[rh * 16 + quad * 4 + r][ch] = pes[r];
        edb[rh * 16 + quad * 4 + r][ch] = ped[r];
      }
    __syncthreads();
    if (tid < 32) {
      int m = tid;
      int v = turn_row_map(by * 32 + m, t);
      es[v * 4 + bx] = esb[m][0] + esb[m][1];
      ed[v * 4 + bx] = edb[m][0] + edb[m][1];
    }
  }
}

// one block per (b,t): recompute node scores from es/ed/adj, softmax over 128,
// weighted mean of h, atomicAdd into out (zeroed by t=5 k_turn idle blocks)
__global__ void __launch_bounds__(256)
k_pool(const int* __restrict__ cnt, const unsigned short* __restrict__ adj,
       const float* __restrict__ es, const float* __restrict__ ed,
       const unsigned short* __restrict__ hbh, const unsigned short* __restrict__ hbl,
       float* __restrict__ out) {
  __shared__ float a[128];
  __shared__ float red[8];
  int bt = blockIdx.x, base = bt * 128, tid = threadIdx.x;
  {
    int n = tid >> 1, v = base + n;
    int deg = cnt[v]; if (deg > MAXDEG) deg = MAXDEG;
    const unsigned short* row = adj + (size_t)v * MAXDEG;
    float part = 0.f;
#pragma unroll
    for (int hh = 0; hh < 2; hh++) {
      int h = (tid & 1) * 2 + hh;
      float edv = ed[v * 4 + h];
      float den = 0.f;
      for (int j0 = 0; j0 < deg; j0 += 4) {
#pragma unroll
        for (int u = 0; u < 4; u++) {
          if (j0 + u < deg) {
            int s = row[j0 + u];
            float lg = es[s * 4 + h] + edv;
            lg = lg >= 0.f ? lg : 0.2f * lg;
            den += __expf(lg);
          }
        }
      }
      part += den / (den + 1e-9f);
    }
    part += __shfl_xor(part, 1);
    if ((tid & 1) == 0) a[n] = 0.25f * part;
  }
  __syncthreads();
  float sv = (tid < 128) ? a[tid] : -1e30f;
  float m = sv;
#pragma unroll
  for (int s = 1; s < 64; s <<= 1) m = fmaxf(m, __shfl_xor(m, s));
  if ((tid & 63) == 0) red[tid >> 6] = m;
  __syncthreads();
  float mx = fmaxf(red[0], red[1]);
  float e = (tid < 128) ? __expf(sv - mx) : 0.f;
  if (tid < 128) a[tid] = e;
  float s_ = e;
#pragma unroll
  for (int s = 1; s < 64; s <<= 1) s_ += __shfl_xor(s_, s);
  if ((tid & 63) == 0) red[4 + (tid >> 6)] = s_;
  __syncthreads();
  float sinv = 1.f / ((red[4] + red[5]) * 128.f);
  float acc = 0.f;
  for (int n = 0; n < 128; n++) {
    int idx = (base + n) * 256 + tid;
    acc += a[n] * reconf(hbh[idx], hbl[idx]);
  }
  int b = bt / 6, tt = bt % 6, spk = tt & 1;
  atomicAdd(&out[spk * 4096 + b * 256 + tid], acc * sinv);
}

extern "C" void kernel_launch(void* const* d_in, const int* in_sizes, int n_in,
                              void* d_out, int out_size, void* d_ws, size_t ws_size,
                              hipStream_t stream) {
  const float* emb    = (const float*)d_in[0];
  const float* nmask  = (const float*)d_in[1];
  const float* W      = (const float*)d_in[2];
  const float* a_src  = (const float*)d_in[3];
  const float* a_dst  = (const float*)d_in[4];
  const float* Wz     = (const float*)d_in[5];
  const float* Uz     = (const float*)d_in[6];
  const float* Wr     = (const float*)d_in[7];
  const float* Ur     = (const float*)d_in[8];
  const float* Wn     = (const float*)d_in[9];
  const float* Un     = (const float*)d_in[10];
  const float* bz     = (const float*)d_in[11];
  const float* br     = (const float*)d_in[12];
  const float* bn     = (const float*)d_in[13];
  const int* nodeidx  = (const int*)d_in[14];
  const int* esrc     = (const int*)d_in[15];
  const int* edst     = (const int*)d_in[16];
  float* out = (float*)d_out;

  char* ws = (char*)d_ws;
  size_t off = 0;
  auto carve = [&](size_t bytes) { char* p = ws + off; off += (bytes + 255) & ~(size_t)255; return p; };
  float* Wh     = (float*)carve((size_t)NTOT * 256 * 4);
  unsigned short* hbh = (unsigned short*)carve((size_t)NTOT * 256 * 2);
  unsigned short* hbl = (unsigned short*)carve((size_t)NTOT * 256 * 2);
  unsigned short* mbh = (unsigned short*)carve(2048 * 256 * 2);
  unsigned short* mbl = (unsigned short*)carve(2048 * 256 * 2);
  unsigned short* rbh = (unsigned short*)carve(2048 * 256 * 2);
  unsigned short* rbl = (unsigned short*)carve(2048 * 256 * 2);
  float* es     = (float*)carve(NTOT * 4 * 4);
  float* ed     = (float*)carve(NTOT * 4 * 4);
  float* g1     = (float*)carve(2048 * 512 * 4);
  float* uacc   = (float*)carve((size_t)12288 * 512 * 4);   // 2 banks: t<3 / t>=3
  int*   cnt    = (int*)carve(NTOT * 4);
  int*   flags  = (int*)carve(8192);   // contiguous after cnt: one memset covers both
  unsigned short* adj = (unsigned short*)carve((size_t)NTOT * MAXDEG * 2);
  unsigned short* wth = (unsigned short*)carve(1792 * 256 * 2);
  unsigned short* wtl = (unsigned short*)carve(1792 * 256 * 2);
  if (off > ws_size) return;  // fail cleanly if workspace too small

  hipMemsetAsync(cnt, 0, NTOT * 4 + 8192, stream);   // cnt + flags
  k_prep<<<3952, 256, 0, stream>>>(emb, nmask, nodeidx, W, Wz, Wr, Wn, Uz, Ur, Un,
                                   esrc, edst, cnt, hbh, hbl, wth, wtl, adj);
  k_mf5<<<4608, 256, 0, stream>>>(hbh, hbl, wth, wtl, Wh, uacc, bz, br,
                                  a_src, a_dst, es, ed);

  for (int t = 0; t < 6; t++)
    k_turn<<<768, 256, 0, stream>>>(cnt, adj, es, ed, Wh, wth, wtl, mbh, mbl,
                                    rbh, rbl, g1, uacc, bn, hbh, hbl,
                                    a_src, a_dst, flags, out, t);

  k_pool<<<96, 256, 0, stream>>>(cnt, adj, es, ed, hbh, hbl, out);
}

// Round 6
// 339.568 us; speedup vs baseline: 5.4524x; 5.4524x over previous
//
#include <hip/hip_runtime.h>

#define NTOT 12288
#define MAXDEG 64

typedef __attribute__((ext_vector_type(8))) short bf8_t;   // 8 bf16 (4 VGPRs)
typedef __attribute__((ext_vector_type(4))) float f32x4;   // MFMA C/D frag

// turn-local row r (0..2047) of turn t -> global node id
__device__ __forceinline__ int turn_row_map(int r, int t) {
  return (r >> 7) * 768 + t * 128 + (r & 127);
}

// split fp32 into bf16 hi (truncate) + bf16 lo (truncated residual): ~2^-16 rel
__device__ __forceinline__ void splitbf(float x, unsigned short& hi, unsigned short& lo) {
  unsigned u = __float_as_uint(x);
  hi = (unsigned short)(u >> 16);
  float fh = __uint_as_float(u & 0xFFFF0000u);
  lo = (unsigned short)(__float_as_uint(x - fh) >> 16);
}
__device__ __forceinline__ float reconf(unsigned short hi, unsigned short lo) {
  return __uint_as_float((unsigned)hi << 16) + __uint_as_float((unsigned)lo << 16);
}
__device__ __forceinline__ uint2 pack4(unsigned short a, unsigned short b,
                                       unsigned short c, unsigned short d) {
  return make_uint2((unsigned)a | ((unsigned)b << 16), (unsigned)c | ((unsigned)d << 16));
}

// 32x64-tile split-bf16 GEMM core, K=256, BK=64 (R1-proven; used by bulk mf5)
__device__ __forceinline__ void gemm32x64_k64(
    const unsigned short* __restrict__ ahp, const unsigned short* __restrict__ alp,
    const unsigned short* __restrict__ bhp, const unsigned short* __restrict__ blp,
    unsigned short (&Ah)[32][72], unsigned short (&Al)[32][72],
    unsigned short (&Bh)[64][72], unsigned short (&Bl)[64][72],
    int ar, int aq, int bn_, int bq, int rh, int ch, int quad, int nl,
    f32x4& acc0, f32x4& acc1) {
  for (int k0 = 0; k0 < 256; k0 += 64) {
    *(uint4*)&Ah[ar][aq * 8] = *(const uint4*)(ahp + k0 + aq * 8);
    *(uint4*)&Al[ar][aq * 8] = *(const uint4*)(alp + k0 + aq * 8);
    *(uint4*)&Bh[bn_][bq * 16]     = *(const uint4*)(bhp + k0 + bq * 16);
    *(uint4*)&Bh[bn_][bq * 16 + 8] = *(const uint4*)(bhp + k0 + bq * 16 + 8);
    *(uint4*)&Bl[bn_][bq * 16]     = *(const uint4*)(blp + k0 + bq * 16);
    *(uint4*)&Bl[bn_][bq * 16 + 8] = *(const uint4*)(blp + k0 + bq * 16 + 8);
    __syncthreads();
#pragma unroll
    for (int kk = 0; kk < 64; kk += 32) {
      bf8_t a_h = *(const bf8_t*)&Ah[rh * 16 + nl][kk + quad * 8];
      bf8_t a_l = *(const bf8_t*)&Al[rh * 16 + nl][kk + quad * 8];
      bf8_t bh0 = *(const bf8_t*)&Bh[ch * 32 + nl][kk + quad * 8];
      bf8_t bl0 = *(const bf8_t*)&Bl[ch * 32 + nl][kk + quad * 8];
      bf8_t bh1 = *(const bf8_t*)&Bh[ch * 32 + 16 + nl][kk + quad * 8];
      bf8_t bl1 = *(const bf8_t*)&Bl[ch * 32 + 16 + nl][kk + quad * 8];
      acc0 = __builtin_amdgcn_mfma_f32_16x16x32_bf16(a_h, bh0, acc0, 0, 0, 0);
      acc1 = __builtin_amdgcn_mfma_f32_16x16x32_bf16(a_h, bh1, acc1, 0, 0, 0);
      acc0 = __builtin_amdgcn_mfma_f32_16x16x32_bf16(a_h, bl0, acc0, 0, 0, 0);
      acc1 = __builtin_amdgcn_mfma_f32_16x16x32_bf16(a_h, bl1, acc1, 0, 0, 0);
      acc0 = __builtin_amdgcn_mfma_f32_16x16x32_bf16(a_l, bh0, acc0, 0, 0, 0);
      acc1 = __builtin_amdgcn_mfma_f32_16x16x32_bf16(a_l, bh1, acc1, 0, 0, 0);
    }
    __syncthreads();
  }
}

// BK=128 variant: same MFMA accumulation order (k=0,32,...,224) -> bit-identical
// results; half the barrier pairs, 2x loads in flight per stage. LDS 52KB: 3 blk/CU.
__device__ __forceinline__ void gemm32x64_k128(
    const unsigned short* __restrict__ ahp, const unsigned short* __restrict__ alp,
    const unsigned short* __restrict__ bhp, const unsigned short* __restrict__ blp,
    unsigned short (&Ah)[32][136], unsigned short (&Al)[32][136],
    unsigned short (&Bh)[64][136], unsigned short (&Bl)[64][136],
    int ar, int aq, int bn_, int bq, int rh, int ch, int quad, int nl,
    f32x4& acc0, f32x4& acc1) {
  for (int k0 = 0; k0 < 256; k0 += 128) {
    *(uint4*)&Ah[ar][aq * 16]     = *(const uint4*)(ahp + k0 + aq * 16);
    *(uint4*)&Ah[ar][aq * 16 + 8] = *(const uint4*)(ahp + k0 + aq * 16 + 8);
    *(uint4*)&Al[ar][aq * 16]     = *(const uint4*)(alp + k0 + aq * 16);
    *(uint4*)&Al[ar][aq * 16 + 8] = *(const uint4*)(alp + k0 + aq * 16 + 8);
#pragma unroll
    for (int u = 0; u < 4; u++) {
      *(uint4*)&Bh[bn_][bq * 32 + u * 8] = *(const uint4*)(bhp + k0 + bq * 32 + u * 8);
      *(uint4*)&Bl[bn_][bq * 32 + u * 8] = *(const uint4*)(blp + k0 + bq * 32 + u * 8);
    }
    __syncthreads();
#pragma unroll
    for (int kk = 0; kk < 128; kk += 32) {
      bf8_t a_h = *(const bf8_t*)&Ah[rh * 16 + nl][kk + quad * 8];
      bf8_t a_l = *(const bf8_t*)&Al[rh * 16 + nl][kk + quad * 8];
      bf8_t bh0 = *(const bf8_t*)&Bh[ch * 32 + nl][kk + quad * 8];
      bf8_t bl0 = *(const bf8_t*)&Bl[ch * 32 + nl][kk + quad * 8];
      bf8_t bh1 = *(const bf8_t*)&Bh[ch * 32 + 16 + nl][kk + quad * 8];
      bf8_t bl1 = *(const bf8_t*)&Bl[ch * 32 + 16 + nl][kk + quad * 8];
      acc0 = __builtin_amdgcn_mfma_f32_16x16x32_bf16(a_h, bh0, acc0, 0, 0, 0);
      acc1 = __builtin_amdgcn_mfma_f32_16x16x32_bf16(a_h, bh1, acc1, 0, 0, 0);
      acc0 = __builtin_amdgcn_mfma_f32_16x16x32_bf16(a_h, bl0, acc0, 0, 0, 0);
      acc1 = __builtin_amdgcn_mfma_f32_16x16x32_bf16(a_h, bl1, acc1, 0, 0, 0);
      acc0 = __builtin_amdgcn_mfma_f32_16x16x32_bf16(a_l, bh0, acc0, 0, 0, 0);
      acc1 = __builtin_amdgcn_mfma_f32_16x16x32_bf16(a_l, bh1, acc1, 0, 0, 0);
    }
    __syncthreads();
  }
}

// ---------------- fused prologue: feat | wconv (LDS transpose) | adj ----------------
__global__ void __launch_bounds__(256)
k_prep(const float* __restrict__ emb, const float* __restrict__ nmask,
       const int* __restrict__ nodeidx,
       const float* __restrict__ W, const float* __restrict__ Wz,
       const float* __restrict__ Wr, const float* __restrict__ Wn,
       const float* __restrict__ Uz, const float* __restrict__ Ur,
       const float* __restrict__ Un,
       const int* __restrict__ esrc, const int* __restrict__ edst, int* __restrict__ cnt,
       unsigned short* __restrict__ hbh, unsigned short* __restrict__ hbl,
       unsigned short* __restrict__ wth, unsigned short* __restrict__ wtl,
       unsigned short* __restrict__ adj) {
  int l = blockIdx.x, tid = threadIdx.x;
  if (l < 3072) {            // feat: NTOT*64 float4 -> bf planes only
    int i = l * 256 + tid;
    int row = i >> 6;
    int src = nodeidx[row];
    float m = nmask[src];
    float4 v = ((const float4*)emb)[(size_t)src * 64 + (i & 63)];
    v.x *= m; v.y *= m; v.z *= m; v.w *= m;
    unsigned short h0,l0,h1,l1,h2,l2,h3,l3;
    splitbf(v.x,h0,l0); splitbf(v.y,h1,l1); splitbf(v.z,h2,l2); splitbf(v.w,h3,l3);
    int o = row * 256 + (i & 63) * 4;
    *(uint2*)(hbh + o) = pack4(h0,h1,h2,h3);
    *(uint2*)(hbl + o) = pack4(l0,l1,l2,l3);
  } else if (l < 3184) {     // wconv: 112 blocks = 7 matrices x 16 (64x64) tiles
    __shared__ float ldt[64][65];
    int bidx = l - 3072;
    int g = bidx >> 4, ti = bidx & 15;
    int tk = (ti & 3) * 64, tn = (ti >> 2) * 64;
    const float* M = g==0?W : g==1?Wz : g==2?Wr : g==3?Wn : g==4?Uz : g==5?Ur : Un;
#pragma unroll
    for (int p = 0; p < 16; p++) {
      int r = p * 4 + (tid >> 6);            // k-local row
      ldt[r][tid & 63] = M[(size_t)(tk + r) * 256 + tn + (tid & 63)];  // coalesced
    }
    __syncthreads();
#pragma unroll
    for (int p = 0; p < 16; p++) {
      int nl_ = p * 4 + (tid >> 6);          // n-local
      int kl = tid & 63;                     // k-local
      float v = ldt[kl][nl_];
      unsigned short hh, ll; splitbf(v, hh, ll);
      int idx = (g * 256 + tn + nl_) * 256 + tk + kl;   // wth[n][k], coalesced in k
      wth[idx] = hh; wtl[idx] = ll;
    }
  } else {                   // adj
    int e = (l - 3184) * 256 + tid;
    int d = edst[e];
    int pos = atomicAdd(&cnt[d], 1);
    if (pos < MAXDEG) adj[(size_t)d * MAXDEG + pos] = (unsigned short)esrc[e];
  }
}

// -------- bulk GEMM: Wh/es/ed all nodes + uacc banks, 32x64 tile, BK=64 (R1) --------
__global__ void __launch_bounds__(256)
k_mf5(const unsigned short* __restrict__ aph, const unsigned short* __restrict__ apl,
      const unsigned short* __restrict__ wth, const unsigned short* __restrict__ wtl,
      float* __restrict__ Wh, float* __restrict__ uacc,
      const float* __restrict__ bz, const float* __restrict__ br,
      const float* __restrict__ asrc, const float* __restrict__ adst,
      float* __restrict__ es, float* __restrict__ ed) {
  __shared__ __align__(16) unsigned short Ah[32][72], Al[32][72];
  __shared__ __align__(16) unsigned short Bh[64][72], Bl[64][72];
  __shared__ float esb[32][2], edb[32][2];
  int l = blockIdx.x, tid = threadIdx.x;
  int q = (l < 1536) ? 0 : (l < 3072 ? 1 : 2);
  int bx, by;
  if (q == 0) { bx = (l & 31) >> 3; by = (l >> 5) * 8 + (l & 7); }                 // 4 x 384
  else { int l2 = l - (q == 1 ? 1536 : 3072); bx = (l2 & 63) >> 3; by = (l2 >> 6) * 8 + (l2 & 7); }  // 8 x 192

  int ar = tid >> 3, aq = tid & 7;
  int bn_ = tid >> 2, bq = tid & 3;
  int gmA = by * 32 + ar;
  int arow;
  if (q == 0) arow = gmA;
  else arow = (gmA / 384) * 768 + (((q == 2) ? 3 : 0) + ((gmA % 384) >> 7)) * 128 + (gmA & 127);
  const unsigned short* ahp = aph + (size_t)arow * 256;
  const unsigned short* alp = apl + (size_t)arow * 256;
  int nbase = (q == 0) ? bx * 64 : 1024 + bx * 64;
  const unsigned short* bhp = wth + (size_t)(nbase + bn_) * 256;
  const unsigned short* blp = wtl + (size_t)(nbase + bn_) * 256;

  int lane = tid & 63, wv = tid >> 6;
  int rh = wv >> 1, ch = wv & 1;
  int quad = lane >> 4, nl = lane & 15;
  f32x4 acc0 = {0.f, 0.f, 0.f, 0.f}, acc1 = {0.f, 0.f, 0.f, 0.f};
  gemm32x64_k64(ahp, alp, bhp, blp, Ah, Al, Bh, Bl, ar, aq, bn_, bq, rh, ch, quad, nl, acc0, acc1);

  int gr = by * 32 + rh * 16 + quad * 4;
  if (q != 0) {  // uacc epilogue (bank0 rows [0,6144), bank1 [6144,12288))
    int rbase = (q == 2) ? 6144 : 0;
#pragma unroll
    for (int r = 0; r < 4; r++) {
      int grr = gr + r;
#pragma unroll
      for (int ct = 0; ct < 2; ct++) {
        float D = (ct == 0) ? acc0[r] : acc1[r];
        int col = bx * 64 + ch * 32 + ct * 16 + nl;
        float bias = (col < 256) ? bz[col] : br[col - 256];
        uacc[(size_t)(rbase + grr) * 512 + col] = D + bias;
      }
    }
  } else {  // Wh + es/ed epilogue
    int c0 = bx * 64 + ch * 32 + nl, c1 = c0 + 16;
    float a0 = asrc[c0], a1 = asrc[c1], d0 = adst[c0], d1 = adst[c1];
    float pes[4], ped[4];
#pragma unroll
    for (int r = 0; r < 4; r++) {
      int v = gr + r;
      float x0 = acc0[r], x1 = acc1[r];
      Wh[(size_t)v * 256 + c0] = x0;
      Wh[(size_t)v * 256 + c1] = x1;
      pes[r] = x0 * a0 + x1 * a1;
      ped[r] = x0 * d0 + x1 * d1;
    }
#pragma unroll
    for (int m = 1; m < 16; m <<= 1)
#pragma unroll
      for (int r = 0; r < 4; r++) {
        pes[r] += __shfl_xor(pes[r], m);
        ped[r] += __shfl_xor(ped[r], m);
      }
    if (nl == 0)
#pragma unroll
      for (int r = 0; r < 4; r++) {
        esb[rh * 16 + quad * 4 + r][ch] = pes[r];
        edb[rh * 16 + quad * 4 + r][ch] = ped[r];
      }
    __syncthreads();
    if (tid < 32) {
      int m = tid;
      int v = by * 32 + m;
      es[v * 4 + bx] = esb[m][0] + esb[m][1];
      ed[v * 4 + bx] = edb[m][0] + edb[m][1];
    }
  }
}

// ---- per-turn Wh/es/ed refresh for rows of turn tu: 256 blocks, 32x64, BK=128 ----
__global__ void __launch_bounds__(256)
k_upd(const unsigned short* __restrict__ hbh, const unsigned short* __restrict__ hbl,
      const unsigned short* __restrict__ wth, const unsigned short* __restrict__ wtl,
      float* __restrict__ Wh, const float* __restrict__ asrc, const float* __restrict__ adst,
      float* __restrict__ es, float* __restrict__ ed, int tu) {
  __shared__ __align__(16) unsigned short Ah[32][136], Al[32][136];
  __shared__ __align__(16) unsigned short Bh[64][136], Bl[64][136];
  __shared__ float esb[32][2], edb[32][2];
  int l = blockIdx.x, tid = threadIdx.x;
  int bx = (l & 31) >> 3, by = (l >> 5) * 8 + (l & 7);   // 4 x 64

  int ar = tid >> 3, aq = tid & 7;
  int bn_ = tid >> 2, bq = tid & 3;
  int arow = turn_row_map(by * 32 + ar, tu);
  const unsigned short* ahp = hbh + (size_t)arow * 256;
  const unsigned short* alp = hbl + (size_t)arow * 256;
  int nbase = bx * 64;                      // W
  const unsigned short* bhp = wth + (size_t)(nbase + bn_) * 256;
  const unsigned short* blp = wtl + (size_t)(nbase + bn_) * 256;

  int lane = tid & 63, wv = tid >> 6;
  int rh = wv >> 1, ch = wv & 1;
  int quad = lane >> 4, nl = lane & 15;
  f32x4 acc0 = {0.f, 0.f, 0.f, 0.f}, acc1 = {0.f, 0.f, 0.f, 0.f};
  gemm32x64_k128(ahp, alp, bhp, blp, Ah, Al, Bh, Bl, ar, aq, bn_, bq, rh, ch, quad, nl, acc0, acc1);

  int gr = by * 32 + rh * 16 + quad * 4;
  int c0 = bx * 64 + ch * 32 + nl, c1 = c0 + 16;
  float a0 = asrc[c0], a1 = asrc[c1], d0 = adst[c0], d1 = adst[c1];
  float pes[4], ped[4];
#pragma unroll
  for (int r = 0; r < 4; r++) {
    int v = turn_row_map(gr + r, tu);
    float x0 = acc0[r], x1 = acc1[r];
    Wh[(size_t)v * 256 + c0] = x0;
    Wh[(size_t)v * 256 + c1] = x1;
    pes[r] = x0 * a0 + x1 * a1;
    ped[r] = x0 * d0 + x1 * d1;
  }
#pragma unroll
  for (int m = 1; m < 16; m <<= 1)
#pragma unroll
    for (int r = 0; r < 4; r++) {
      pes[r] += __shfl_xor(pes[r], m);
      ped[r] += __shfl_xor(ped[r], m);
    }
  if (nl == 0)
#pragma unroll
    for (int r = 0; r < 4; r++) {
      esb[rh * 16 + quad * 4 + r][ch] = pes[r];
      edb[rh * 16 + quad * 4 + r][ch] = ped[r];
    }
  __syncthreads();
  if (tid < 32) {
    int m = tid;
    int v = turn_row_map(by * 32 + m, tu);
    es[v * 4 + bx] = esb[m][0] + esb[m][1];
    ed[v * 4 + bx] = edb[m][0] + edb[m][1];
  }
}

// -------- per-dst attention softmax + message for turn-t rows (grid 512, 1 row/wave) ----
__global__ void __launch_bounds__(256)
k_attn(const int* __restrict__ cnt, const unsigned short* __restrict__ adj,
       const float* __restrict__ es, const float* __restrict__ ed,
       const float* __restrict__ Wh,
       unsigned short* __restrict__ mbh, unsigned short* __restrict__ mbl, int t) {
  __shared__ float wgs[4][64][4];
  __shared__ unsigned short ssrc[4][64];
  int wv = threadIdx.x >> 6;
  int w = blockIdx.x * 4 + wv;
  int lane = threadIdx.x & 63;
  int v = turn_row_map(w, t);
  int deg = cnt[v];
  if (deg > MAXDEG) deg = MAXDEG;
  const unsigned short* row = adj + (size_t)v * MAXDEG;
  float edq = ed[v * 4 + (lane & 3)];
  float dsum = 0.f;
  int passes = (deg + 15) >> 4;
  for (int p = 0; p < passes; p++) {
    int jj = p * 16 + (lane >> 2);
    if (jj < deg) {
      int s = row[jj];
      float lg = es[s * 4 + (lane & 3)] + edq;
      lg = lg >= 0.f ? lg : 0.2f * lg;
      float wgv = __expf(lg);
      wgs[wv][jj][lane & 3] = wgv;
      if ((lane & 3) == 0) ssrc[wv][jj] = (unsigned short)s;
      dsum += wgv;
    } else {
      wgs[wv][jj][lane & 3] = 0.f;
      if ((lane & 3) == 0) ssrc[wv][jj] = 0;
    }
  }
  dsum += __shfl_xor(dsum, 4);
  dsum += __shfl_xor(dsum, 8);
  dsum += __shfl_xor(dsum, 16);
  dsum += __shfl_xor(dsum, 32);
  float invq = 1.f / (dsum + 1e-9f);
  float myinv = __shfl(invq, lane >> 4);  // lanes 0..3 hold heads 0..3
  float4 acc = make_float4(0.f, 0.f, 0.f, 0.f);
  int deg4 = (deg + 3) & ~3;              // wgs zero-padded to deg4
  for (int j0 = 0; j0 < deg4; j0 += 4) {
#pragma unroll
    for (int u = 0; u < 4; u++) {
      int s = ssrc[wv][j0 + u];
      float wgv = wgs[wv][j0 + u][lane >> 4];
      float4 x = ((const float4*)Wh)[(size_t)s * 64 + lane];
      acc.x += wgv * x.x; acc.y += wgv * x.y;
      acc.z += wgv * x.z; acc.w += wgv * x.w;
    }
  }
  unsigned short h0,l0,h1,l1,h2,l2,h3,l3;
  splitbf(acc.x * myinv, h0, l0); splitbf(acc.y * myinv, h1, l1);
  splitbf(acc.z * myinv, h2, l2); splitbf(acc.w * myinv, h3, l3);
  int o = w * 256 + lane * 4;
  *(uint2*)(mbh + o) = pack4(h0, h1, h2, h3);
  *(uint2*)(mbl + o) = pack4(l0, l1, l2, l3);
}

// -------- gates: msg@{Wz,Wr,Wn}, 768 blocks, BK=128 --------
__global__ void __launch_bounds__(256)
k_mf2(const unsigned short* __restrict__ mbh, const unsigned short* __restrict__ mbl,
      const unsigned short* __restrict__ wth, const unsigned short* __restrict__ wtl,
      const float* __restrict__ uacc, const float* __restrict__ bn,
      const unsigned short* __restrict__ hbh, const unsigned short* __restrict__ hbl,
      float* __restrict__ g1, unsigned short* __restrict__ rbh, unsigned short* __restrict__ rbl,
      int t) {
  __shared__ __align__(16) unsigned short Ah[32][136], Al[32][136];
  __shared__ __align__(16) unsigned short Bh[64][136], Bl[64][136];
  int l = blockIdx.x, tid = threadIdx.x;
  int bx = (l % 96) >> 3, by = (l / 96) * 8 + (l & 7);   // 12 x 64

  int ar = tid >> 3, aq = tid & 7;
  int bn_ = tid >> 2, bq = tid & 3;
  int gmA = by * 32 + ar;
  const unsigned short* ahp = mbh + (size_t)gmA * 256;
  const unsigned short* alp = mbl + (size_t)gmA * 256;
  int nbase = 256 + bx * 64;
  const unsigned short* bhp = wth + (size_t)(nbase + bn_) * 256;
  const unsigned short* blp = wtl + (size_t)(nbase + bn_) * 256;

  int lane = tid & 63, wv = tid >> 6;
  int rh = wv >> 1, ch = wv & 1;
  int quad = lane >> 4, nl = lane & 15;
  f32x4 acc0 = {0.f, 0.f, 0.f, 0.f}, acc1 = {0.f, 0.f, 0.f, 0.f};
  gemm32x64_k128(ahp, alp, bhp, blp, Ah, Al, Bh, Bl, ar, aq, bn_, bq, rh, ch, quad, nl, acc0, acc1);

  int gr = by * 32 + rh * 16 + quad * 4;
  int g = bx >> 2;
  int tm3 = t % 3;
  const float* up = uacc + (size_t)(t >= 3 ? 6144 : 0) * 512;
#pragma unroll
  for (int r = 0; r < 4; r++) {
    int grr = gr + r;
    int v = turn_row_map(grr, t);
    int urow = (grr >> 7) * 384 + tm3 * 128 + (grr & 127);
#pragma unroll
    for (int ct = 0; ct < 2; ct++) {
      float D = (ct == 0) ? acc0[r] : acc1[r];
      int c = (bx & 3) * 64 + ch * 32 + ct * 16 + nl;
      if (g == 0) {
        g1[(size_t)grr * 512 + c] = D + up[(size_t)urow * 512 + c];
      } else if (g == 1) {
        float rpre = D + up[(size_t)urow * 512 + 256 + c];
        float rv = 1.f / (1.f + __expf(-rpre));
        int hidx = v * 256 + c;
        float hv = reconf(hbh[hidx], hbl[hidx]);
        float rhv = rv * hv;
        unsigned short hh, ll; splitbf(rhv, hh, ll);
        rbh[grr * 256 + c] = hh; rbl[grr * 256 + c] = ll;
      } else {
        g1[(size_t)grr * 512 + 256 + c] = D + bn[c];
      }
    }
  }
}

// -------- GRU combine -> h planes; 256 blocks BK=128 (+8 out-zero blocks at t=5) ----
__global__ void __launch_bounds__(256)
k_mf3(const unsigned short* __restrict__ rbh, const unsigned short* __restrict__ rbl,
      const unsigned short* __restrict__ wth, const unsigned short* __restrict__ wtl,
      const float* __restrict__ g1,
      unsigned short* __restrict__ hbh, unsigned short* __restrict__ hbl,
      float* __restrict__ outp, int t) {
  __shared__ __align__(16) unsigned short Ah[32][136], Al[32][136];
  __shared__ __align__(16) unsigned short Bh[64][136], Bl[64][136];
  int l = blockIdx.x, tid = threadIdx.x;
  if (l >= 256) {  // out-zero blocks (only launched at t=5)
    ((float4*)outp)[(l - 256) * 256 + tid] = make_float4(0.f, 0.f, 0.f, 0.f);
    return;
  }
  int bx = (l & 31) >> 3, by = (l >> 5) * 8 + (l & 7);   // 4 x 64

  int ar = tid >> 3, aq = tid & 7;
  int bn_ = tid >> 2, bq = tid & 3;
  int gmA = by * 32 + ar;
  const unsigned short* ahp = rbh + (size_t)gmA * 256;
  const unsigned short* alp = rbl + (size_t)gmA * 256;
  int nbase = 1536 + bx * 64;              // Un
  const unsigned short* bhp = wth + (size_t)(nbase + bn_) * 256;
  const unsigned short* blp = wtl + (size_t)(nbase + bn_) * 256;

  int lane = tid & 63, wv = tid >> 6;
  int rh = wv >> 1, ch = wv & 1;
  int quad = lane >> 4, nl = lane & 15;
  f32x4 acc0 = {0.f, 0.f, 0.f, 0.f}, acc1 = {0.f, 0.f, 0.f, 0.f};
  gemm32x64_k128(ahp, alp, bhp, blp, Ah, Al, Bh, Bl, ar, aq, bn_, bq, rh, ch, quad, nl, acc0, acc1);

  int gr = by * 32 + rh * 16 + quad * 4;
#pragma unroll
  for (int r = 0; r < 4; r++) {
    int grr = gr + r;
    int v = turn_row_map(grr, t);
#pragma unroll
    for (int ct = 0; ct < 2; ct++) {
      float D = (ct == 0) ? acc0[r] : acc1[r];
      int c = bx * 64 + ch * 32 + ct * 16 + nl;
      float zpre = g1[(size_t)grr * 512 + c];
      float npre = g1[(size_t)grr * 512 + 256 + c] + D;
      float z = 1.f / (1.f + __expf(-zpre));
      float n = tanhf(npre);
      int hidx = v * 256 + c;
      float hv = reconf(hbh[hidx], hbl[hidx]);
      float hn = (1.f - z) * hv + z * n;
      unsigned short hh, ll; splitbf(hn, hh, ll);
      hbh[hidx] = hh;
      hbl[hidx] = ll;
    }
  }
}

// one block per (b,t): recompute node scores from es/ed/adj (R3-verified), softmax
// over 128, weighted mean of h planes, atomicAdd into out (zeroed by t=5 mf3 blocks)
__global__ void __launch_bounds__(256)
k_pool(const int* __restrict__ cnt, const unsigned short* __restrict__ adj,
       const float* __restrict__ es, const float* __restrict__ ed,
       const unsigned short* __restrict__ hbh, const unsigned short* __restrict__ hbl,
       float* __restrict__ out) {
  __shared__ float a[128];
  __shared__ float red[8];
  int bt = blockIdx.x, base = bt * 128, tid = threadIdx.x;
  {
    int n = tid >> 1, v = base + n;
    int deg = cnt[v]; if (deg > MAXDEG) deg = MAXDEG;
    const unsigned short* row = adj + (size_t)v * MAXDEG;
    float part = 0.f;
#pragma unroll
    for (int hh = 0; hh < 2; hh++) {
      int h = (tid & 1) * 2 + hh;
      float edv = ed[v * 4 + h];
      float den = 0.f;
      for (int j0 = 0; j0 < deg; j0 += 4) {
#pragma unroll
        for (int u = 0; u < 4; u++) {
          if (j0 + u < deg) {
            int s = row[j0 + u];
            float lg = es[s * 4 + h] + edv;
            lg = lg >= 0.f ? lg : 0.2f * lg;
            den += __expf(lg);
          }
        }
      }
      part += den / (den + 1e-9f);
    }
    part += __shfl_xor(part, 1);
    if ((tid & 1) == 0) a[n] = 0.25f * part;
  }
  __syncthreads();
  float sv = (tid < 128) ? a[tid] : -1e30f;
  float m = sv;
#pragma unroll
  for (int s = 1; s < 64; s <<= 1) m = fmaxf(m, __shfl_xor(m, s));
  if ((tid & 63) == 0) red[tid >> 6] = m;
  __syncthreads();
  float mx = fmaxf(red[0], red[1]);
  float e = (tid < 128) ? __expf(sv - mx) : 0.f;
  if (tid < 128) a[tid] = e;
  float s_ = e;
#pragma unroll
  for (int s = 1; s < 64; s <<= 1) s_ += __shfl_xor(s_, s);
  if ((tid & 63) == 0) red[4 + (tid >> 6)] = s_;
  __syncthreads();
  float sinv = 1.f / ((red[4] + red[5]) * 128.f);
  float acc = 0.f;
  for (int n = 0; n < 128; n++) {
    int idx = (base + n) * 256 + tid;
    acc += a[n] * reconf(hbh[idx], hbl[idx]);
  }
  int b = bt / 6, tt = bt % 6, spk = tt & 1;
  atomicAdd(&out[spk * 4096 + b * 256 + tid], acc * sinv);
}

extern "C" void kernel_launch(void* const* d_in, const int* in_sizes, int n_in,
                              void* d_out, int out_size, void* d_ws, size_t ws_size,
                              hipStream_t stream) {
  const float* emb    = (const float*)d_in[0];
  const float* nmask  = (const float*)d_in[1];
  const float* W      = (const float*)d_in[2];
  const float* a_src  = (const float*)d_in[3];
  const float* a_dst  = (const float*)d_in[4];
  const float* Wz     = (const float*)d_in[5];
  const float* Uz     = (const float*)d_in[6];
  const float* Wr     = (const float*)d_in[7];
  const float* Ur     = (const float*)d_in[8];
  const float* Wn     = (const float*)d_in[9];
  const float* Un     = (const float*)d_in[10];
  const float* bz     = (const float*)d_in[11];
  const float* br     = (const float*)d_in[12];
  const float* bn     = (const float*)d_in[13];
  const int* nodeidx  = (const int*)d_in[14];
  const int* esrc     = (const int*)d_in[15];
  const int* edst     = (const int*)d_in[16];
  float* out = (float*)d_out;

  char* ws = (char*)d_ws;
  size_t off = 0;
  auto carve = [&](size_t bytes) { char* p = ws + off; off += (bytes + 255) & ~(size_t)255; return p; };
  float* Wh     = (float*)carve((size_t)NTOT * 256 * 4);
  unsigned short* hbh = (unsigned short*)carve((size_t)NTOT * 256 * 2);
  unsigned short* hbl = (unsigned short*)carve((size_t)NTOT * 256 * 2);
  unsigned short* mbh = (unsigned short*)carve(2048 * 256 * 2);
  unsigned short* mbl = (unsigned short*)carve(2048 * 256 * 2);
  unsigned short* rbh = (unsigned short*)carve(2048 * 256 * 2);
  unsigned short* rbl = (unsigned short*)carve(2048 * 256 * 2);
  float* es     = (float*)carve(NTOT * 4 * 4);
  float* ed     = (float*)carve(NTOT * 4 * 4);
  float* g1     = (float*)carve(2048 * 512 * 4);
  float* uacc   = (float*)carve((size_t)12288 * 512 * 4);   // 2 banks: t<3 / t>=3
  int*   cnt    = (int*)carve(NTOT * 4);
  unsigned short* adj = (unsigned short*)carve((size_t)NTOT * MAXDEG * 2);
  unsigned short* wth = (unsigned short*)carve(1792 * 256 * 2);
  unsigned short* wtl = (unsigned short*)carve(1792 * 256 * 2);
  if (off > ws_size) return;  // fail cleanly if workspace too small

  hipMemsetAsync(cnt, 0, NTOT * 4, stream);
  k_prep<<<3952, 256, 0, stream>>>(emb, nmask, nodeidx, W, Wz, Wr, Wn, Uz, Ur, Un,
                                   esrc, edst, cnt, hbh, hbl, wth, wtl, adj);
  k_mf5<<<4608, 256, 0, stream>>>(hbh, hbl, wth, wtl, Wh, uacc, bz, br,
                                  a_src, a_dst, es, ed);

  for (int t = 0; t < 6; t++) {
    if (t > 0)
      k_upd<<<256, 256, 0, stream>>>(hbh, hbl, wth, wtl, Wh, a_src, a_dst, es, ed, t - 1);
    k_attn<<<512, 256, 0, stream>>>(cnt, adj, es, ed, Wh, mbh, mbl, t);
    k_mf2<<<768, 256, 0, stream>>>(mbh, mbl, wth, wtl, uacc, bn, hbh, hbl,
                                   g1, rbh, rbl, t);
    k_mf3<<<(t == 5 ? 264 : 256), 256, 0, stream>>>(rbh, rbl, wth, wtl, g1,
                                                    hbh, hbl, out, t);
  }

  k_pool<<<96, 256, 0, stream>>>(cnt, adj, es, ed, hbh, hbl, out);
}

// Round 7
// 337.123 us; speedup vs baseline: 5.4919x; 1.0073x over previous
//
#include <hip/hip_runtime.h>

#define NTOT 12288
#define MAXDEG 64

typedef __attribute__((ext_vector_type(8))) short bf8_t;   // 8 bf16 (4 VGPRs)
typedef __attribute__((ext_vector_type(4))) float f32x4;   // MFMA C/D frag

// turn-local row r (0..2047) of turn t -> global node id
__device__ __forceinline__ int turn_row_map(int r, int t) {
  return (r >> 7) * 768 + t * 128 + (r & 127);
}

// split fp32 into bf16 hi (truncate) + bf16 lo (truncated residual): ~2^-16 rel
__device__ __forceinline__ void splitbf(float x, unsigned short& hi, unsigned short& lo) {
  unsigned u = __float_as_uint(x);
  hi = (unsigned short)(u >> 16);
  float fh = __uint_as_float(u & 0xFFFF0000u);
  lo = (unsigned short)(__float_as_uint(x - fh) >> 16);
}
__device__ __forceinline__ float reconf(unsigned short hi, unsigned short lo) {
  return __uint_as_float((unsigned)hi << 16) + __uint_as_float((unsigned)lo << 16);
}
__device__ __forceinline__ uint2 pack4(unsigned short a, unsigned short b,
                                       unsigned short c, unsigned short d) {
  return make_uint2((unsigned)a | ((unsigned)b << 16), (unsigned)c | ((unsigned)d << 16));
}

// 32x64-tile split-bf16 GEMM core, K=256, BK=64 (R1-proven; LDS 27KB -> 5 blk/CU)
__device__ __forceinline__ void gemm32x64_k64(
    const unsigned short* __restrict__ ahp, const unsigned short* __restrict__ alp,
    const unsigned short* __restrict__ bhp, const unsigned short* __restrict__ blp,
    unsigned short (&Ah)[32][72], unsigned short (&Al)[32][72],
    unsigned short (&Bh)[64][72], unsigned short (&Bl)[64][72],
    int ar, int aq, int bn_, int bq, int rh, int ch, int quad, int nl,
    f32x4& acc0, f32x4& acc1) {
  for (int k0 = 0; k0 < 256; k0 += 64) {
    *(uint4*)&Ah[ar][aq * 8] = *(const uint4*)(ahp + k0 + aq * 8);
    *(uint4*)&Al[ar][aq * 8] = *(const uint4*)(alp + k0 + aq * 8);
    *(uint4*)&Bh[bn_][bq * 16]     = *(const uint4*)(bhp + k0 + bq * 16);
    *(uint4*)&Bh[bn_][bq * 16 + 8] = *(const uint4*)(bhp + k0 + bq * 16 + 8);
    *(uint4*)&Bl[bn_][bq * 16]     = *(const uint4*)(blp + k0 + bq * 16);
    *(uint4*)&Bl[bn_][bq * 16 + 8] = *(const uint4*)(blp + k0 + bq * 16 + 8);
    __syncthreads();
#pragma unroll
    for (int kk = 0; kk < 64; kk += 32) {
      bf8_t a_h = *(const bf8_t*)&Ah[rh * 16 + nl][kk + quad * 8];
      bf8_t a_l = *(const bf8_t*)&Al[rh * 16 + nl][kk + quad * 8];
      bf8_t bh0 = *(const bf8_t*)&Bh[ch * 32 + nl][kk + quad * 8];
      bf8_t bl0 = *(const bf8_t*)&Bl[ch * 32 + nl][kk + quad * 8];
      bf8_t bh1 = *(const bf8_t*)&Bh[ch * 32 + 16 + nl][kk + quad * 8];
      bf8_t bl1 = *(const bf8_t*)&Bl[ch * 32 + 16 + nl][kk + quad * 8];
      acc0 = __builtin_amdgcn_mfma_f32_16x16x32_bf16(a_h, bh0, acc0, 0, 0, 0);
      acc1 = __builtin_amdgcn_mfma_f32_16x16x32_bf16(a_h, bh1, acc1, 0, 0, 0);
      acc0 = __builtin_amdgcn_mfma_f32_16x16x32_bf16(a_h, bl0, acc0, 0, 0, 0);
      acc1 = __builtin_amdgcn_mfma_f32_16x16x32_bf16(a_h, bl1, acc1, 0, 0, 0);
      acc0 = __builtin_amdgcn_mfma_f32_16x16x32_bf16(a_l, bh0, acc0, 0, 0, 0);
      acc1 = __builtin_amdgcn_mfma_f32_16x16x32_bf16(a_l, bh1, acc1, 0, 0, 0);
    }
    __syncthreads();
  }
}

// ---------------- fused prologue: feat | wconv (LDS transpose) | adj ----------------
__global__ void __launch_bounds__(256)
k_prep(const float* __restrict__ emb, const float* __restrict__ nmask,
       const int* __restrict__ nodeidx,
       const float* __restrict__ W, const float* __restrict__ Wz,
       const float* __restrict__ Wr, const float* __restrict__ Wn,
       const float* __restrict__ Uz, const float* __restrict__ Ur,
       const float* __restrict__ Un,
       const int* __restrict__ esrc, const int* __restrict__ edst, int* __restrict__ cnt,
       unsigned short* __restrict__ hbh, unsigned short* __restrict__ hbl,
       unsigned short* __restrict__ wth, unsigned short* __restrict__ wtl,
       unsigned short* __restrict__ adj) {
  int l = blockIdx.x, tid = threadIdx.x;
  if (l < 3072) {            // feat: NTOT*64 float4 -> bf planes only
    int i = l * 256 + tid;
    int row = i >> 6;
    int src = nodeidx[row];
    float m = nmask[src];
    float4 v = ((const float4*)emb)[(size_t)src * 64 + (i & 63)];
    v.x *= m; v.y *= m; v.z *= m; v.w *= m;
    unsigned short h0,l0,h1,l1,h2,l2,h3,l3;
    splitbf(v.x,h0,l0); splitbf(v.y,h1,l1); splitbf(v.z,h2,l2); splitbf(v.w,h3,l3);
    int o = row * 256 + (i & 63) * 4;
    *(uint2*)(hbh + o) = pack4(h0,h1,h2,h3);
    *(uint2*)(hbl + o) = pack4(l0,l1,l2,l3);
  } else if (l < 3184) {     // wconv: 112 blocks = 7 matrices x 16 (64x64) tiles
    __shared__ float ldt[64][65];
    int bidx = l - 3072;
    int g = bidx >> 4, ti = bidx & 15;
    int tk = (ti & 3) * 64, tn = (ti >> 2) * 64;
    const float* M = g==0?W : g==1?Wz : g==2?Wr : g==3?Wn : g==4?Uz : g==5?Ur : Un;
#pragma unroll
    for (int p = 0; p < 16; p++) {
      int r = p * 4 + (tid >> 6);            // k-local row
      ldt[r][tid & 63] = M[(size_t)(tk + r) * 256 + tn + (tid & 63)];  // coalesced
    }
    __syncthreads();
#pragma unroll
    for (int p = 0; p < 16; p++) {
      int nl_ = p * 4 + (tid >> 6);          // n-local
      int kl = tid & 63;                     // k-local
      float v = ldt[kl][nl_];
      unsigned short hh, ll; splitbf(v, hh, ll);
      int idx = (g * 256 + tn + nl_) * 256 + tk + kl;   // wth[n][k], coalesced in k
      wth[idx] = hh; wtl[idx] = ll;
    }
  } else {                   // adj
    int e = (l - 3184) * 256 + tid;
    int d = edst[e];
    int pos = atomicAdd(&cnt[d], 1);
    if (pos < MAXDEG) adj[(size_t)d * MAXDEG + pos] = (unsigned short)esrc[e];
  }
}

// -------- bulk GEMM: Wh/es/ed all nodes + uacc banks, 32x64 tile, BK=64 (R1) --------
__global__ void __launch_bounds__(256)
k_mf5(const unsigned short* __restrict__ aph, const unsigned short* __restrict__ apl,
      const unsigned short* __restrict__ wth, const unsigned short* __restrict__ wtl,
      float* __restrict__ Wh, float* __restrict__ uacc,
      const float* __restrict__ bz, const float* __restrict__ br,
      const float* __restrict__ asrc, const float* __restrict__ adst,
      float* __restrict__ es, float* __restrict__ ed) {
  __shared__ __align__(16) unsigned short Ah[32][72], Al[32][72];
  __shared__ __align__(16) unsigned short Bh[64][72], Bl[64][72];
  __shared__ float esb[32][2], edb[32][2];
  int l = blockIdx.x, tid = threadIdx.x;
  int q = (l < 1536) ? 0 : (l < 3072 ? 1 : 2);
  int bx, by;
  if (q == 0) { bx = (l & 31) >> 3; by = (l >> 5) * 8 + (l & 7); }                 // 4 x 384
  else { int l2 = l - (q == 1 ? 1536 : 3072); bx = (l2 & 63) >> 3; by = (l2 >> 6) * 8 + (l2 & 7); }  // 8 x 192

  int ar = tid >> 3, aq = tid & 7;
  int bn_ = tid >> 2, bq = tid & 3;
  int gmA = by * 32 + ar;
  int arow;
  if (q == 0) arow = gmA;
  else arow = (gmA / 384) * 768 + (((q == 2) ? 3 : 0) + ((gmA % 384) >> 7)) * 128 + (gmA & 127);
  const unsigned short* ahp = aph + (size_t)arow * 256;
  const unsigned short* alp = apl + (size_t)arow * 256;
  int nbase = (q == 0) ? bx * 64 : 1024 + bx * 64;
  const unsigned short* bhp = wth + (size_t)(nbase + bn_) * 256;
  const unsigned short* blp = wtl + (size_t)(nbase + bn_) * 256;

  int lane = tid & 63, wv = tid >> 6;
  int rh = wv >> 1, ch = wv & 1;
  int quad = lane >> 4, nl = lane & 15;
  f32x4 acc0 = {0.f, 0.f, 0.f, 0.f}, acc1 = {0.f, 0.f, 0.f, 0.f};
  gemm32x64_k64(ahp, alp, bhp, blp, Ah, Al, Bh, Bl, ar, aq, bn_, bq, rh, ch, quad, nl, acc0, acc1);

  int gr = by * 32 + rh * 16 + quad * 4;
  if (q != 0) {  // uacc epilogue (bank0 rows [0,6144), bank1 [6144,12288))
    int rbase = (q == 2) ? 6144 : 0;
#pragma unroll
    for (int r = 0; r < 4; r++) {
      int grr = gr + r;
#pragma unroll
      for (int ct = 0; ct < 2; ct++) {
        float D = (ct == 0) ? acc0[r] : acc1[r];
        int col = bx * 64 + ch * 32 + ct * 16 + nl;
        float bias = (col < 256) ? bz[col] : br[col - 256];
        uacc[(size_t)(rbase + grr) * 512 + col] = D + bias;
      }
    }
  } else {  // Wh + es/ed epilogue
    int c0 = bx * 64 + ch * 32 + nl, c1 = c0 + 16;
    float a0 = asrc[c0], a1 = asrc[c1], d0 = adst[c0], d1 = adst[c1];
    float pes[4], ped[4];
#pragma unroll
    for (int r = 0; r < 4; r++) {
      int v = gr + r;
      float x0 = acc0[r], x1 = acc1[r];
      Wh[(size_t)v * 256 + c0] = x0;
      Wh[(size_t)v * 256 + c1] = x1;
      pes[r] = x0 * a0 + x1 * a1;
      ped[r] = x0 * d0 + x1 * d1;
    }
#pragma unroll
    for (int m = 1; m < 16; m <<= 1)
#pragma unroll
      for (int r = 0; r < 4; r++) {
        pes[r] += __shfl_xor(pes[r], m);
        ped[r] += __shfl_xor(ped[r], m);
      }
    if (nl == 0)
#pragma unroll
      for (int r = 0; r < 4; r++) {
        esb[rh * 16 + quad * 4 + r][ch] = pes[r];
        edb[rh * 16 + quad * 4 + r][ch] = ped[r];
      }
    __syncthreads();
    if (tid < 32) {
      int m = tid;
      int v = by * 32 + m;
      es[v * 4 + bx] = esb[m][0] + esb[m][1];
      ed[v * 4 + bx] = edb[m][0] + edb[m][1];
    }
  }
}

// ---- per-turn Wh/es/ed refresh for rows of turn tu: 256 blocks, 32x64, BK=64 ----
// (mf5-q0 pattern with turn_row_map; replaces R1's 128-block register-B gemm16)
__global__ void __launch_bounds__(256)
k_upd(const unsigned short* __restrict__ hbh, const unsigned short* __restrict__ hbl,
      const unsigned short* __restrict__ wth, const unsigned short* __restrict__ wtl,
      float* __restrict__ Wh, const float* __restrict__ asrc, const float* __restrict__ adst,
      float* __restrict__ es, float* __restrict__ ed, int tu) {
  __shared__ __align__(16) unsigned short Ah[32][72], Al[32][72];
  __shared__ __align__(16) unsigned short Bh[64][72], Bl[64][72];
  __shared__ float esb[32][2], edb[32][2];
  int l = blockIdx.x, tid = threadIdx.x;
  int bx = (l & 31) >> 3, by = (l >> 5) * 8 + (l & 7);   // 4 x 64

  int ar = tid >> 3, aq = tid & 7;
  int bn_ = tid >> 2, bq = tid & 3;
  int arow = turn_row_map(by * 32 + ar, tu);
  const unsigned short* ahp = hbh + (size_t)arow * 256;
  const unsigned short* alp = hbl + (size_t)arow * 256;
  int nbase = bx * 64;                      // W
  const unsigned short* bhp = wth + (size_t)(nbase + bn_) * 256;
  const unsigned short* blp = wtl + (size_t)(nbase + bn_) * 256;

  int lane = tid & 63, wv = tid >> 6;
  int rh = wv >> 1, ch = wv & 1;
  int quad = lane >> 4, nl = lane & 15;
  f32x4 acc0 = {0.f, 0.f, 0.f, 0.f}, acc1 = {0.f, 0.f, 0.f, 0.f};
  gemm32x64_k64(ahp, alp, bhp, blp, Ah, Al, Bh, Bl, ar, aq, bn_, bq, rh, ch, quad, nl, acc0, acc1);

  int gr = by * 32 + rh * 16 + quad * 4;
  int c0 = bx * 64 + ch * 32 + nl, c1 = c0 + 16;
  float a0 = asrc[c0], a1 = asrc[c1], d0 = adst[c0], d1 = adst[c1];
  float pes[4], ped[4];
#pragma unroll
  for (int r = 0; r < 4; r++) {
    int v = turn_row_map(gr + r, tu);
    float x0 = acc0[r], x1 = acc1[r];
    Wh[(size_t)v * 256 + c0] = x0;
    Wh[(size_t)v * 256 + c1] = x1;
    pes[r] = x0 * a0 + x1 * a1;
    ped[r] = x0 * d0 + x1 * d1;
  }
#pragma unroll
  for (int m = 1; m < 16; m <<= 1)
#pragma unroll
    for (int r = 0; r < 4; r++) {
      pes[r] += __shfl_xor(pes[r], m);
      ped[r] += __shfl_xor(ped[r], m);
    }
  if (nl == 0)
#pragma unroll
    for (int r = 0; r < 4; r++) {
      esb[rh * 16 + quad * 4 + r][ch] = pes[r];
      edb[rh * 16 + quad * 4 + r][ch] = ped[r];
    }
  __syncthreads();
  if (tid < 32) {
    int m = tid;
    int v = turn_row_map(by * 32 + m, tu);
    es[v * 4 + bx] = esb[m][0] + esb[m][1];
    ed[v * 4 + bx] = edb[m][0] + edb[m][1];
  }
}

// -------- per-dst attention softmax + message for turn-t rows (grid 512, 1 row/wave) ----
__global__ void __launch_bounds__(256)
k_attn(const int* __restrict__ cnt, const unsigned short* __restrict__ adj,
       const float* __restrict__ es, const float* __restrict__ ed,
       const float* __restrict__ Wh,
       unsigned short* __restrict__ mbh, unsigned short* __restrict__ mbl, int t) {
  __shared__ float wgs[4][64][4];
  __shared__ unsigned short ssrc[4][64];
  int wv = threadIdx.x >> 6;
  int w = blockIdx.x * 4 + wv;
  int lane = threadIdx.x & 63;
  int v = turn_row_map(w, t);
  int deg = cnt[v];
  if (deg > MAXDEG) deg = MAXDEG;
  const unsigned short* row = adj + (size_t)v * MAXDEG;
  float edq = ed[v * 4 + (lane & 3)];
  float dsum = 0.f;
  int passes = (deg + 15) >> 4;
  for (int p = 0; p < passes; p++) {
    int jj = p * 16 + (lane >> 2);
    if (jj < deg) {
      int s = row[jj];
      float lg = es[s * 4 + (lane & 3)] + edq;
      lg = lg >= 0.f ? lg : 0.2f * lg;
      float wgv = __expf(lg);
      wgs[wv][jj][lane & 3] = wgv;
      if ((lane & 3) == 0) ssrc[wv][jj] = (unsigned short)s;
      dsum += wgv;
    } else {
      wgs[wv][jj][lane & 3] = 0.f;
      if ((lane & 3) == 0) ssrc[wv][jj] = 0;
    }
  }
  dsum += __shfl_xor(dsum, 4);
  dsum += __shfl_xor(dsum, 8);
  dsum += __shfl_xor(dsum, 16);
  dsum += __shfl_xor(dsum, 32);
  float invq = 1.f / (dsum + 1e-9f);
  float myinv = __shfl(invq, lane >> 4);  // lanes 0..3 hold heads 0..3
  float4 acc = make_float4(0.f, 0.f, 0.f, 0.f);
  int deg4 = (deg + 3) & ~3;              // wgs zero-padded to deg4
  for (int j0 = 0; j0 < deg4; j0 += 4) {
#pragma unroll
    for (int u = 0; u < 4; u++) {
      int s = ssrc[wv][j0 + u];
      float wgv = wgs[wv][j0 + u][lane >> 4];
      float4 x = ((const float4*)Wh)[(size_t)s * 64 + lane];
      acc.x += wgv * x.x; acc.y += wgv * x.y;
      acc.z += wgv * x.z; acc.w += wgv * x.w;
    }
  }
  unsigned short h0,l0,h1,l1,h2,l2,h3,l3;
  splitbf(acc.x * myinv, h0, l0); splitbf(acc.y * myinv, h1, l1);
  splitbf(acc.z * myinv, h2, l2); splitbf(acc.w * myinv, h3, l3);
  int o = w * 256 + lane * 4;
  *(uint2*)(mbh + o) = pack4(h0, h1, h2, h3);
  *(uint2*)(mbl + o) = pack4(l0, l1, l2, l3);
}

// -------- gates: msg@{Wz,Wr,Wn}, 768 blocks, BK=64 (R1) --------
__global__ void __launch_bounds__(256)
k_mf2(const unsigned short* __restrict__ mbh, const unsigned short* __restrict__ mbl,
      const unsigned short* __restrict__ wth, const unsigned short* __restrict__ wtl,
      const float* __restrict__ uacc, const float* __restrict__ bn,
      const unsigned short* __restrict__ hbh, const unsigned short* __restrict__ hbl,
      float* __restrict__ g1, unsigned short* __restrict__ rbh, unsigned short* __restrict__ rbl,
      int t) {
  __shared__ __align__(16) unsigned short Ah[32][72], Al[32][72];
  __shared__ __align__(16) unsigned short Bh[64][72], Bl[64][72];
  int l = blockIdx.x, tid = threadIdx.x;
  int bx = (l % 96) >> 3, by = (l / 96) * 8 + (l & 7);   // 12 x 64

  int ar = tid >> 3, aq = tid & 7;
  int bn_ = tid >> 2, bq = tid & 3;
  int gmA = by * 32 + ar;
  const unsigned short* ahp = mbh + (size_t)gmA * 256;
  const unsigned short* alp = mbl + (size_t)gmA * 256;
  int nbase = 256 + bx * 64;
  const unsigned short* bhp = wth + (size_t)(nbase + bn_) * 256;
  const unsigned short* blp = wtl + (size_t)(nbase + bn_) * 256;

  int lane = tid & 63, wv = tid >> 6;
  int rh = wv >> 1, ch = wv & 1;
  int quad = lane >> 4, nl = lane & 15;
  f32x4 acc0 = {0.f, 0.f, 0.f, 0.f}, acc1 = {0.f, 0.f, 0.f, 0.f};
  gemm32x64_k64(ahp, alp, bhp, blp, Ah, Al, Bh, Bl, ar, aq, bn_, bq, rh, ch, quad, nl, acc0, acc1);

  int gr = by * 32 + rh * 16 + quad * 4;
  int g = bx >> 2;
  int tm3 = t % 3;
  const float* up = uacc + (size_t)(t >= 3 ? 6144 : 0) * 512;
#pragma unroll
  for (int r = 0; r < 4; r++) {
    int grr = gr + r;
    int v = turn_row_map(grr, t);
    int urow = (grr >> 7) * 384 + tm3 * 128 + (grr & 127);
#pragma unroll
    for (int ct = 0; ct < 2; ct++) {
      float D = (ct == 0) ? acc0[r] : acc1[r];
      int c = (bx & 3) * 64 + ch * 32 + ct * 16 + nl;
      if (g == 0) {
        g1[(size_t)grr * 512 + c] = D + up[(size_t)urow * 512 + c];
      } else if (g == 1) {
        float rpre = D + up[(size_t)urow * 512 + 256 + c];
        float rv = 1.f / (1.f + __expf(-rpre));
        int hidx = v * 256 + c;
        float hv = reconf(hbh[hidx], hbl[hidx]);
        float rhv = rv * hv;
        unsigned short hh, ll; splitbf(rhv, hh, ll);
        rbh[grr * 256 + c] = hh; rbl[grr * 256 + c] = ll;
      } else {
        g1[(size_t)grr * 512 + 256 + c] = D + bn[c];
      }
    }
  }
}

// -------- GRU combine -> h planes; 256 blocks BK=64 (+8 out-zero blocks at t=5) ----
__global__ void __launch_bounds__(256)
k_mf3(const unsigned short* __restrict__ rbh, const unsigned short* __restrict__ rbl,
      const unsigned short* __restrict__ wth, const unsigned short* __restrict__ wtl,
      const float* __restrict__ g1,
      unsigned short* __restrict__ hbh, unsigned short* __restrict__ hbl,
      float* __restrict__ outp, int t) {
  __shared__ __align__(16) unsigned short Ah[32][72], Al[32][72];
  __shared__ __align__(16) unsigned short Bh[64][72], Bl[64][72];
  int l = blockIdx.x, tid = threadIdx.x;
  if (l >= 256) {  // out-zero blocks (only launched at t=5)
    ((float4*)outp)[(l - 256) * 256 + tid] = make_float4(0.f, 0.f, 0.f, 0.f);
    return;
  }
  int bx = (l & 31) >> 3, by = (l >> 5) * 8 + (l & 7);   // 4 x 64

  int ar = tid >> 3, aq = tid & 7;
  int bn_ = tid >> 2, bq = tid & 3;
  int gmA = by * 32 + ar;
  const unsigned short* ahp = rbh + (size_t)gmA * 256;
  const unsigned short* alp = rbl + (size_t)gmA * 256;
  int nbase = 1536 + bx * 64;              // Un
  const unsigned short* bhp = wth + (size_t)(nbase + bn_) * 256;
  const unsigned short* blp = wtl + (size_t)(nbase + bn_) * 256;

  int lane = tid & 63, wv = tid >> 6;
  int rh = wv >> 1, ch = wv & 1;
  int quad = lane >> 4, nl = lane & 15;
  f32x4 acc0 = {0.f, 0.f, 0.f, 0.f}, acc1 = {0.f, 0.f, 0.f, 0.f};
  gemm32x64_k64(ahp, alp, bhp, blp, Ah, Al, Bh, Bl, ar, aq, bn_, bq, rh, ch, quad, nl, acc0, acc1);

  int gr = by * 32 + rh * 16 + quad * 4;
#pragma unroll
  for (int r = 0; r < 4; r++) {
    int grr = gr + r;
    int v = turn_row_map(grr, t);
#pragma unroll
    for (int ct = 0; ct < 2; ct++) {
      float D = (ct == 0) ? acc0[r] : acc1[r];
      int c = bx * 64 + ch * 32 + ct * 16 + nl;
      float zpre = g1[(size_t)grr * 512 + c];
      float npre = g1[(size_t)grr * 512 + 256 + c] + D;
      float z = 1.f / (1.f + __expf(-zpre));
      float n = tanhf(npre);
      int hidx = v * 256 + c;
      float hv = reconf(hbh[hidx], hbl[hidx]);
      float hn = (1.f - z) * hv + z * n;
      unsigned short hh, ll; splitbf(hn, hh, ll);
      hbh[hidx] = hh;
      hbl[hidx] = ll;
    }
  }
}

// one block per (b,t): recompute node scores from es/ed/adj (R3-verified), softmax
// over 128, weighted mean of h planes, atomicAdd into out (zeroed by t=5 mf3 blocks)
__global__ void __launch_bounds__(256)
k_pool(const int* __restrict__ cnt, const unsigned short* __restrict__ adj,
       const float* __restrict__ es, const float* __restrict__ ed,
       const unsigned short* __restrict__ hbh, const unsigned short* __restrict__ hbl,
       float* __restrict__ out) {
  __shared__ float a[128];
  __shared__ float red[8];
  int bt = blockIdx.x, base = bt * 128, tid = threadIdx.x;
  {
    int n = tid >> 1, v = base + n;
    int deg = cnt[v]; if (deg > MAXDEG) deg = MAXDEG;
    const unsigned short* row = adj + (size_t)v * MAXDEG;
    float part = 0.f;
#pragma unroll
    for (int hh = 0; hh < 2; hh++) {
      int h = (tid & 1) * 2 + hh;
      float edv = ed[v * 4 + h];
      float den = 0.f;
      for (int j0 = 0; j0 < deg; j0 += 4) {
#pragma unroll
        for (int u = 0; u < 4; u++) {
          if (j0 + u < deg) {
            int s = row[j0 + u];
            float lg = es[s * 4 + h] + edv;
            lg = lg >= 0.f ? lg : 0.2f * lg;
            den += __expf(lg);
          }
        }
      }
      part += den / (den + 1e-9f);
    }
    part += __shfl_xor(part, 1);
    if ((tid & 1) == 0) a[n] = 0.25f * part;
  }
  __syncthreads();
  float sv = (tid < 128) ? a[tid] : -1e30f;
  float m = sv;
#pragma unroll
  for (int s = 1; s < 64; s <<= 1) m = fmaxf(m, __shfl_xor(m, s));
  if ((tid & 63) == 0) red[tid >> 6] = m;
  __syncthreads();
  float mx = fmaxf(red[0], red[1]);
  float e = (tid < 128) ? __expf(sv - mx) : 0.f;
  if (tid < 128) a[tid] = e;
  float s_ = e;
#pragma unroll
  for (int s = 1; s < 64; s <<= 1) s_ += __shfl_xor(s_, s);
  if ((tid & 63) == 0) red[4 + (tid >> 6)] = s_;
  __syncthreads();
  float sinv = 1.f / ((red[4] + red[5]) * 128.f);
  float acc = 0.f;
  for (int n = 0; n < 128; n++) {
    int idx = (base + n) * 256 + tid;
    acc += a[n] * reconf(hbh[idx], hbl[idx]);
  }
  int b = bt / 6, tt = bt % 6, spk = tt & 1;
  atomicAdd(&out[spk * 4096 + b * 256 + tid], acc * sinv);
}

extern "C" void kernel_launch(void* const* d_in, const int* in_sizes, int n_in,
                              void* d_out, int out_size, void* d_ws, size_t ws_size,
                              hipStream_t stream) {
  const float* emb    = (const float*)d_in[0];
  const float* nmask  = (const float*)d_in[1];
  const float* W      = (const float*)d_in[2];
  const float* a_src  = (const float*)d_in[3];
  const float* a_dst  = (const float*)d_in[4];
  const float* Wz     = (const float*)d_in[5];
  const float* Uz     = (const float*)d_in[6];
  const float* Wr     = (const float*)d_in[7];
  const float* Ur     = (const float*)d_in[8];
  const float* Wn     = (const float*)d_in[9];
  const float* Un     = (const float*)d_in[10];
  const float* bz     = (const float*)d_in[11];
  const float* br     = (const float*)d_in[12];
  const float* bn     = (const float*)d_in[13];
  const int* nodeidx  = (const int*)d_in[14];
  const int* esrc     = (const int*)d_in[15];
  const int* edst     = (const int*)d_in[16];
  float* out = (float*)d_out;

  char* ws = (char*)d_ws;
  size_t off = 0;
  auto carve = [&](size_t bytes) { char* p = ws + off; off += (bytes + 255) & ~(size_t)255; return p; };
  float* Wh     = (float*)carve((size_t)NTOT * 256 * 4);
  unsigned short* hbh = (unsigned short*)carve((size_t)NTOT * 256 * 2);
  unsigned short* hbl = (unsigned short*)carve((size_t)NTOT * 256 * 2);
  unsigned short* mbh = (unsigned short*)carve(2048 * 256 * 2);
  unsigned short* mbl = (unsigned short*)carve(2048 * 256 * 2);
  unsigned short* rbh = (unsigned short*)carve(2048 * 256 * 2);
  unsigned short* rbl = (unsigned short*)carve(2048 * 256 * 2);
  float* es     = (float*)carve(NTOT * 4 * 4);
  float* ed     = (float*)carve(NTOT * 4 * 4);
  float* g1     = (float*)carve(2048 * 512 * 4);
  float* uacc   = (float*)carve((size_t)12288 * 512 * 4);   // 2 banks: t<3 / t>=3
  int*   cnt    = (int*)carve(NTOT * 4);
  unsigned short* adj = (unsigned short*)carve((size_t)NTOT * MAXDEG * 2);
  unsigned short* wth = (unsigned short*)carve(1792 * 256 * 2);
  unsigned short* wtl = (unsigned short*)carve(1792 * 256 * 2);
  if (off > ws_size) return;  // fail cleanly if workspace too small

  hipMemsetAsync(cnt, 0, NTOT * 4, stream);
  k_prep<<<3952, 256, 0, stream>>>(emb, nmask, nodeidx, W, Wz, Wr, Wn, Uz, Ur, Un,
                                   esrc, edst, cnt, hbh, hbl, wth, wtl, adj);
  k_mf5<<<4608, 256, 0, stream>>>(hbh, hbl, wth, wtl, Wh, uacc, bz, br,
                                  a_src, a_dst, es, ed);

  for (int t = 0; t < 6; t++) {
    if (t > 0)
      k_upd<<<256, 256, 0, stream>>>(hbh, hbl, wth, wtl, Wh, a_src, a_dst, es, ed, t - 1);
    k_attn<<<512, 256, 0, stream>>>(cnt, adj, es, ed, Wh, mbh, mbl, t);
    k_mf2<<<768, 256, 0, stream>>>(mbh, mbl, wth, wtl, uacc, bn, hbh, hbl,
                                   g1, rbh, rbl, t);
    k_mf3<<<(t == 5 ? 264 : 256), 256, 0, stream>>>(rbh, rbl, wth, wtl, g1,
                                                    hbh, hbl, out, t);
  }

  k_pool<<<96, 256, 0, stream>>>(cnt, adj, es, ed, hbh, hbl, out);
}

// Round 8
// 313.414 us; speedup vs baseline: 5.9074x; 1.0756x over previous
//
#include <hip/hip_runtime.h>

#define NTOT 12288
#define MAXDEG 64

typedef __attribute__((ext_vector_type(8))) short bf8_t;   // 8 bf16 (4 VGPRs)
typedef __attribute__((ext_vector_type(4))) float f32x4;   // MFMA C/D frag

// turn-local row r (0..2047) of turn t -> global node id
__device__ __forceinline__ int turn_row_map(int r, int t) {
  return (r >> 7) * 768 + t * 128 + (r & 127);
}

// split fp32 into bf16 hi (truncate) + bf16 lo (truncated residual): ~2^-16 rel
__device__ __forceinline__ void splitbf(float x, unsigned short& hi, unsigned short& lo) {
  unsigned u = __float_as_uint(x);
  hi = (unsigned short)(u >> 16);
  float fh = __uint_as_float(u & 0xFFFF0000u);
  lo = (unsigned short)(__float_as_uint(x - fh) >> 16);
}
__device__ __forceinline__ float reconf(unsigned short hi, unsigned short lo) {
  return __uint_as_float((unsigned)hi << 16) + __uint_as_float((unsigned)lo << 16);
}
__device__ __forceinline__ uint2 pack4(unsigned short a, unsigned short b,
                                       unsigned short c, unsigned short d) {
  return make_uint2((unsigned)a | ((unsigned)b << 16), (unsigned)c | ((unsigned)d << 16));
}

// 32x64-tile split-bf16 GEMM core, K=256, BK=64 (R1-proven; LDS 27KB -> 5 blk/CU)
__device__ __forceinline__ void gemm32x64_k64(
    const unsigned short* __restrict__ ahp, const unsigned short* __restrict__ alp,
    const unsigned short* __restrict__ bhp, const unsigned short* __restrict__ blp,
    unsigned short (&Ah)[32][72], unsigned short (&Al)[32][72],
    unsigned short (&Bh)[64][72], unsigned short (&Bl)[64][72],
    int ar, int aq, int bn_, int bq, int rh, int ch, int quad, int nl,
    f32x4& acc0, f32x4& acc1) {
  for (int k0 = 0; k0 < 256; k0 += 64) {
    *(uint4*)&Ah[ar][aq * 8] = *(const uint4*)(ahp + k0 + aq * 8);
    *(uint4*)&Al[ar][aq * 8] = *(const uint4*)(alp + k0 + aq * 8);
    *(uint4*)&Bh[bn_][bq * 16]     = *(const uint4*)(bhp + k0 + bq * 16);
    *(uint4*)&Bh[bn_][bq * 16 + 8] = *(const uint4*)(bhp + k0 + bq * 16 + 8);
    *(uint4*)&Bl[bn_][bq * 16]     = *(const uint4*)(blp + k0 + bq * 16);
    *(uint4*)&Bl[bn_][bq * 16 + 8] = *(const uint4*)(blp + k0 + bq * 16 + 8);
    __syncthreads();
#pragma unroll
    for (int kk = 0; kk < 64; kk += 32) {
      bf8_t a_h = *(const bf8_t*)&Ah[rh * 16 + nl][kk + quad * 8];
      bf8_t a_l = *(const bf8_t*)&Al[rh * 16 + nl][kk + quad * 8];
      bf8_t bh0 = *(const bf8_t*)&Bh[ch * 32 + nl][kk + quad * 8];
      bf8_t bl0 = *(const bf8_t*)&Bl[ch * 32 + nl][kk + quad * 8];
      bf8_t bh1 = *(const bf8_t*)&Bh[ch * 32 + 16 + nl][kk + quad * 8];
      bf8_t bl1 = *(const bf8_t*)&Bl[ch * 32 + 16 + nl][kk + quad * 8];
      acc0 = __builtin_amdgcn_mfma_f32_16x16x32_bf16(a_h, bh0, acc0, 0, 0, 0);
      acc1 = __builtin_amdgcn_mfma_f32_16x16x32_bf16(a_h, bh1, acc1, 0, 0, 0);
      acc0 = __builtin_amdgcn_mfma_f32_16x16x32_bf16(a_h, bl0, acc0, 0, 0, 0);
      acc1 = __builtin_amdgcn_mfma_f32_16x16x32_bf16(a_h, bl1, acc1, 0, 0, 0);
      acc0 = __builtin_amdgcn_mfma_f32_16x16x32_bf16(a_l, bh0, acc0, 0, 0, 0);
      acc1 = __builtin_amdgcn_mfma_f32_16x16x32_bf16(a_l, bh1, acc1, 0, 0, 0);
    }
    __syncthreads();
  }
}

// ---------------- fused prologue: feat | wconv (LDS transpose) | adj ----------------
__global__ void __launch_bounds__(256)
k_prep(const float* __restrict__ emb, const float* __restrict__ nmask,
       const int* __restrict__ nodeidx,
       const float* __restrict__ W, const float* __restrict__ Wz,
       const float* __restrict__ Wr, const float* __restrict__ Wn,
       const float* __restrict__ Uz, const float* __restrict__ Ur,
       const float* __restrict__ Un,
       const int* __restrict__ esrc, const int* __restrict__ edst, int* __restrict__ cnt,
       unsigned short* __restrict__ hbh, unsigned short* __restrict__ hbl,
       unsigned short* __restrict__ wth, unsigned short* __restrict__ wtl,
       unsigned short* __restrict__ adj) {
  int l = blockIdx.x, tid = threadIdx.x;
  if (l < 3072) {            // feat: NTOT*64 float4 -> bf planes only
    int i = l * 256 + tid;
    int row = i >> 6;
    int src = nodeidx[row];
    float m = nmask[src];
    float4 v = ((const float4*)emb)[(size_t)src * 64 + (i & 63)];
    v.x *= m; v.y *= m; v.z *= m; v.w *= m;
    unsigned short h0,l0,h1,l1,h2,l2,h3,l3;
    splitbf(v.x,h0,l0); splitbf(v.y,h1,l1); splitbf(v.z,h2,l2); splitbf(v.w,h3,l3);
    int o = row * 256 + (i & 63) * 4;
    *(uint2*)(hbh + o) = pack4(h0,h1,h2,h3);
    *(uint2*)(hbl + o) = pack4(l0,l1,l2,l3);
  } else if (l < 3184) {     // wconv: 112 blocks = 7 matrices x 16 (64x64) tiles
    __shared__ float ldt[64][65];
    int bidx = l - 3072;
    int g = bidx >> 4, ti = bidx & 15;
    int tk = (ti & 3) * 64, tn = (ti >> 2) * 64;
    const float* M = g==0?W : g==1?Wz : g==2?Wr : g==3?Wn : g==4?Uz : g==5?Ur : Un;
#pragma unroll
    for (int p = 0; p < 16; p++) {
      int r = p * 4 + (tid >> 6);            // k-local row
      ldt[r][tid & 63] = M[(size_t)(tk + r) * 256 + tn + (tid & 63)];  // coalesced
    }
    __syncthreads();
#pragma unroll
    for (int p = 0; p < 16; p++) {
      int nl_ = p * 4 + (tid >> 6);          // n-local
      int kl = tid & 63;                     // k-local
      float v = ldt[kl][nl_];
      unsigned short hh, ll; splitbf(v, hh, ll);
      int idx = (g * 256 + tn + nl_) * 256 + tk + kl;   // wth[n][k], coalesced in k
      wth[idx] = hh; wtl[idx] = ll;
    }
  } else {                   // adj
    int e = (l - 3184) * 256 + tid;
    int d = edst[e];
    int pos = atomicAdd(&cnt[d], 1);
    if (pos < MAXDEG) adj[(size_t)d * MAXDEG + pos] = (unsigned short)esrc[e];
  }
}

// -------- bulk GEMM: 32x128 tiles (A re-read halved). grid 2304:
// q0 [0,768): Wh+es/ed (2 bx x 384 by); q1 [768,1536): uacc bank0; q2: bank1 --------
__global__ void __launch_bounds__(256)
k_mf5(const unsigned short* __restrict__ aph, const unsigned short* __restrict__ apl,
      const unsigned short* __restrict__ wth, const unsigned short* __restrict__ wtl,
      float* __restrict__ Wh, float* __restrict__ uacc,
      const float* __restrict__ bz, const float* __restrict__ br,
      const float* __restrict__ asrc, const float* __restrict__ adst,
      float* __restrict__ es, float* __restrict__ ed) {
  __shared__ __align__(16) unsigned short Ah[32][72], Al[32][72];
  __shared__ __align__(16) unsigned short Bh[128][72], Bl[128][72];
  __shared__ float esb[32][2], edb[32][2];
  int l = blockIdx.x, tid = threadIdx.x;
  int q = (l < 768) ? 0 : (l < 1536 ? 1 : 2);
  int bx, by;
  if (q == 0) { bx = (l & 15) >> 3; by = (l >> 4) * 8 + (l & 7); }                 // 2 x 384
  else { int l2 = l - (q == 1 ? 768 : 1536); bx = (l2 & 31) >> 3; by = (l2 >> 5) * 8 + (l2 & 7); }  // 4 x 192

  int ar = tid >> 3, aq = tid & 7;
  int bn_ = tid >> 1, bq = tid & 1;   // B staging: 128 n-rows x 2 threads
  int gmA = by * 32 + ar;
  int arow;
  if (q == 0) arow = gmA;
  else arow = (gmA / 384) * 768 + (((q == 2) ? 3 : 0) + ((gmA % 384) >> 7)) * 128 + (gmA & 127);
  const unsigned short* ahp = aph + (size_t)arow * 256;
  const unsigned short* alp = apl + (size_t)arow * 256;
  int nbase = (q == 0) ? bx * 128 : 1024 + bx * 128;
  const unsigned short* bhp = wth + (size_t)(nbase + bn_) * 256;
  const unsigned short* blp = wtl + (size_t)(nbase + bn_) * 256;

  int lane = tid & 63, wv = tid >> 6;
  int rh = wv >> 1, ch = wv & 1;      // wave: 16 rows x 64 cols (cols = ch*64..+64)
  int quad = lane >> 4, nl = lane & 15;
  f32x4 acc[4];
#pragma unroll
  for (int ct = 0; ct < 4; ct++) acc[ct] = (f32x4){0.f, 0.f, 0.f, 0.f};

  for (int k0 = 0; k0 < 256; k0 += 64) {
    *(uint4*)&Ah[ar][aq * 8] = *(const uint4*)(ahp + k0 + aq * 8);
    *(uint4*)&Al[ar][aq * 8] = *(const uint4*)(alp + k0 + aq * 8);
#pragma unroll
    for (int u = 0; u < 4; u++) {
      *(uint4*)&Bh[bn_][bq * 32 + u * 8] = *(const uint4*)(bhp + k0 + bq * 32 + u * 8);
      *(uint4*)&Bl[bn_][bq * 32 + u * 8] = *(const uint4*)(blp + k0 + bq * 32 + u * 8);
    }
    __syncthreads();
#pragma unroll
    for (int kk = 0; kk < 64; kk += 32) {
      bf8_t a_h = *(const bf8_t*)&Ah[rh * 16 + nl][kk + quad * 8];
      bf8_t a_l = *(const bf8_t*)&Al[rh * 16 + nl][kk + quad * 8];
#pragma unroll
      for (int ct = 0; ct < 4; ct++) {
        bf8_t bh = *(const bf8_t*)&Bh[ch * 64 + ct * 16 + nl][kk + quad * 8];
        bf8_t bl = *(const bf8_t*)&Bl[ch * 64 + ct * 16 + nl][kk + quad * 8];
        acc[ct] = __builtin_amdgcn_mfma_f32_16x16x32_bf16(a_h, bh, acc[ct], 0, 0, 0);
        acc[ct] = __builtin_amdgcn_mfma_f32_16x16x32_bf16(a_h, bl, acc[ct], 0, 0, 0);
        acc[ct] = __builtin_amdgcn_mfma_f32_16x16x32_bf16(a_l, bh, acc[ct], 0, 0, 0);
      }
    }
    __syncthreads();
  }

  int gr = by * 32 + rh * 16 + quad * 4;
  if (q != 0) {  // uacc epilogue (bank0 rows [0,6144), bank1 [6144,12288))
    int rbase = (q == 2) ? 6144 : 0;
#pragma unroll
    for (int r = 0; r < 4; r++) {
      int grr = gr + r;
#pragma unroll
      for (int ct = 0; ct < 4; ct++) {
        float D = acc[ct][r];
        int col = bx * 128 + ch * 64 + ct * 16 + nl;
        float bias = (col < 256) ? bz[col] : br[col - 256];
        uacc[(size_t)(rbase + grr) * 512 + col] = D + bias;
      }
    }
  } else {  // Wh + es/ed epilogue; wave's 64 cols == head (bx*2 + ch)
    float pes[4] = {0.f, 0.f, 0.f, 0.f}, ped[4] = {0.f, 0.f, 0.f, 0.f};
#pragma unroll
    for (int ct = 0; ct < 4; ct++) {
      int c = bx * 128 + ch * 64 + ct * 16 + nl;
      float ac = asrc[c], dc = adst[c];
#pragma unroll
      for (int r = 0; r < 4; r++) {
        float D = acc[ct][r];
        Wh[(size_t)(gr + r) * 256 + c] = D;
        pes[r] += D * ac;
        ped[r] += D * dc;
      }
    }
#pragma unroll
    for (int m = 1; m < 16; m <<= 1)
#pragma unroll
      for (int r = 0; r < 4; r++) {
        pes[r] += __shfl_xor(pes[r], m);
        ped[r] += __shfl_xor(ped[r], m);
      }
    if (nl == 0)
#pragma unroll
      for (int r = 0; r < 4; r++) {
        esb[rh * 16 + quad * 4 + r][ch] = pes[r];
        edb[rh * 16 + quad * 4 + r][ch] = ped[r];
      }
    __syncthreads();
    if (tid < 64) {
      int m = tid & 31, hh = tid >> 5;
      int v = by * 32 + m;
      es[v * 4 + bx * 2 + hh] = esb[m][hh];
      ed[v * 4 + bx * 2 + hh] = edb[m][hh];
    }
  }
}

// ---- per-turn Wh/es/ed refresh for rows of turn tu: 256 blocks, 32x64, BK=64 ----
__global__ void __launch_bounds__(256)
k_upd(const unsigned short* __restrict__ hbh, const unsigned short* __restrict__ hbl,
      const unsigned short* __restrict__ wth, const unsigned short* __restrict__ wtl,
      float* __restrict__ Wh, const float* __restrict__ asrc, const float* __restrict__ adst,
      float* __restrict__ es, float* __restrict__ ed, int tu) {
  __shared__ __align__(16) unsigned short Ah[32][72], Al[32][72];
  __shared__ __align__(16) unsigned short Bh[64][72], Bl[64][72];
  __shared__ float esb[32][2], edb[32][2];
  int l = blockIdx.x, tid = threadIdx.x;
  int bx = (l & 31) >> 3, by = (l >> 5) * 8 + (l & 7);   // 4 x 64

  int ar = tid >> 3, aq = tid & 7;
  int bn_ = tid >> 2, bq = tid & 3;
  int arow = turn_row_map(by * 32 + ar, tu);
  const unsigned short* ahp = hbh + (size_t)arow * 256;
  const unsigned short* alp = hbl + (size_t)arow * 256;
  int nbase = bx * 64;                      // W
  const unsigned short* bhp = wth + (size_t)(nbase + bn_) * 256;
  const unsigned short* blp = wtl + (size_t)(nbase + bn_) * 256;

  int lane = tid & 63, wv = tid >> 6;
  int rh = wv >> 1, ch = wv & 1;
  int quad = lane >> 4, nl = lane & 15;
  f32x4 acc0 = {0.f, 0.f, 0.f, 0.f}, acc1 = {0.f, 0.f, 0.f, 0.f};
  gemm32x64_k64(ahp, alp, bhp, blp, Ah, Al, Bh, Bl, ar, aq, bn_, bq, rh, ch, quad, nl, acc0, acc1);

  int gr = by * 32 + rh * 16 + quad * 4;
  int c0 = bx * 64 + ch * 32 + nl, c1 = c0 + 16;
  float a0 = asrc[c0], a1 = asrc[c1], d0 = adst[c0], d1 = adst[c1];
  float pes[4], ped[4];
#pragma unroll
  for (int r = 0; r < 4; r++) {
    int v = turn_row_map(gr + r, tu);
    float x0 = acc0[r], x1 = acc1[r];
    Wh[(size_t)v * 256 + c0] = x0;
    Wh[(size_t)v * 256 + c1] = x1;
    pes[r] = x0 * a0 + x1 * a1;
    ped[r] = x0 * d0 + x1 * d1;
  }
#pragma unroll
  for (int m = 1; m < 16; m <<= 1)
#pragma unroll
    for (int r = 0; r < 4; r++) {
      pes[r] += __shfl_xor(pes[r], m);
      ped[r] += __shfl_xor(ped[r], m);
    }
  if (nl == 0)
#pragma unroll
    for (int r = 0; r < 4; r++) {
      esb[rh * 16 + quad * 4 + r][ch] = pes[r];
      edb[rh * 16 + quad * 4 + r][ch] = ped[r];
    }
  __syncthreads();
  if (tid < 32) {
    int m = tid;
    int v = turn_row_map(by * 32 + m, tu);
    es[v * 4 + bx] = esb[m][0] + esb[m][1];
    ed[v * 4 + bx] = edb[m][0] + edb[m][1];
  }
}

// per-dst attention softmax + message (R1 champion version: allnodes pass at t=5
// also emits per-node score = mean over heads of sum of attn into v)
__global__ void __launch_bounds__(256)
k_attn(const int* __restrict__ cnt, const unsigned short* __restrict__ adj,
       const float* __restrict__ es, const float* __restrict__ ed,
       const float* __restrict__ Wh,
       unsigned short* __restrict__ mbh, unsigned short* __restrict__ mbl,
       float* __restrict__ score, int t, int allnodes) {
  __shared__ float wgs[4][64][4];
  __shared__ unsigned short ssrc[4][64];
  int gph = blockIdx.x & 15, j = blockIdx.x >> 4;
  int wv = threadIdx.x >> 6;
  int w = (allnodes ? gph * 768 : gph * 128) + j * 4 + wv;
  int lane = threadIdx.x & 63;
  int v, mrow, storemsg;
  if (allnodes) {
    v = w;
    int bt = v >> 7;
    int tt = bt % 6;
    storemsg = (tt == t);
    mrow = (bt / 6) * 128 + (v & 127);
  } else {
    v = turn_row_map(w, t);
    mrow = w;
    storemsg = 1;
  }
  int deg = cnt[v];
  if (deg > MAXDEG) deg = MAXDEG;
  const unsigned short* row = adj + (size_t)v * MAXDEG;
  float edq = ed[v * 4 + (lane & 3)];
  float dsum = 0.f;
  int passes = (deg + 15) >> 4;
  for (int p = 0; p < passes; p++) {
    int jj = p * 16 + (lane >> 2);
    if (jj < deg) {
      int s = row[jj];
      float lg = es[s * 4 + (lane & 3)] + edq;
      lg = lg >= 0.f ? lg : 0.2f * lg;
      float wgv = __expf(lg);
      wgs[wv][jj][lane & 3] = wgv;
      if ((lane & 3) == 0) ssrc[wv][jj] = (unsigned short)s;
      dsum += wgv;
    } else {
      wgs[wv][jj][lane & 3] = 0.f;
      if ((lane & 3) == 0) ssrc[wv][jj] = 0;
    }
  }
  dsum += __shfl_xor(dsum, 4);
  dsum += __shfl_xor(dsum, 8);
  dsum += __shfl_xor(dsum, 16);
  dsum += __shfl_xor(dsum, 32);
  float invq = 1.f / (dsum + 1e-9f);
  if (allnodes) {
    float val = dsum * invq;        // per-head sum of attn into v
    val += __shfl_xor(val, 1);
    val += __shfl_xor(val, 2);
    if (lane == 0) score[v] = 0.25f * val;
  }
  if (storemsg) {
    float myinv = __shfl(invq, lane >> 4);  // lanes 0..3 hold heads 0..3
    float4 acc = make_float4(0.f, 0.f, 0.f, 0.f);
    int deg4 = (deg + 3) & ~3;              // wgs zero-padded to deg4
    for (int j0 = 0; j0 < deg4; j0 += 4) {
#pragma unroll
      for (int u = 0; u < 4; u++) {
        int s = ssrc[wv][j0 + u];
        float wgv = wgs[wv][j0 + u][lane >> 4];
        float4 x = ((const float4*)Wh)[(size_t)s * 64 + lane];
        acc.x += wgv * x.x; acc.y += wgv * x.y;
        acc.z += wgv * x.z; acc.w += wgv * x.w;
      }
    }
    unsigned short h0,l0,h1,l1,h2,l2,h3,l3;
    splitbf(acc.x * myinv, h0, l0); splitbf(acc.y * myinv, h1, l1);
    splitbf(acc.z * myinv, h2, l2); splitbf(acc.w * myinv, h3, l3);
    int o = mrow * 256 + lane * 4;
    *(uint2*)(mbh + o) = pack4(h0, h1, h2, h3);
    *(uint2*)(mbl + o) = pack4(l0, l1, l2, l3);
  }
}

// -------- gates: msg@{Wz,Wr,Wn}, 768 blocks, BK=64 (R1) --------
__global__ void __launch_bounds__(256)
k_mf2(const unsigned short* __restrict__ mbh, const unsigned short* __restrict__ mbl,
      const unsigned short* __restrict__ wth, const unsigned short* __restrict__ wtl,
      const float* __restrict__ uacc, const float* __restrict__ bn,
      const unsigned short* __restrict__ hbh, const unsigned short* __restrict__ hbl,
      float* __restrict__ g1, unsigned short* __restrict__ rbh, unsigned short* __restrict__ rbl,
      int t) {
  __shared__ __align__(16) unsigned short Ah[32][72], Al[32][72];
  __shared__ __align__(16) unsigned short Bh[64][72], Bl[64][72];
  int l = blockIdx.x, tid = threadIdx.x;
  int bx = (l % 96) >> 3, by = (l / 96) * 8 + (l & 7);   // 12 x 64

  int ar = tid >> 3, aq = tid & 7;
  int bn_ = tid >> 2, bq = tid & 3;
  int gmA = by * 32 + ar;
  const unsigned short* ahp = mbh + (size_t)gmA * 256;
  const unsigned short* alp = mbl + (size_t)gmA * 256;
  int nbase = 256 + bx * 64;
  const unsigned short* bhp = wth + (size_t)(nbase + bn_) * 256;
  const unsigned short* blp = wtl + (size_t)(nbase + bn_) * 256;

  int lane = tid & 63, wv = tid >> 6;
  int rh = wv >> 1, ch = wv & 1;
  int quad = lane >> 4, nl = lane & 15;
  f32x4 acc0 = {0.f, 0.f, 0.f, 0.f}, acc1 = {0.f, 0.f, 0.f, 0.f};
  gemm32x64_k64(ahp, alp, bhp, blp, Ah, Al, Bh, Bl, ar, aq, bn_, bq, rh, ch, quad, nl, acc0, acc1);

  int gr = by * 32 + rh * 16 + quad * 4;
  int g = bx >> 2;
  int tm3 = t % 3;
  const float* up = uacc + (size_t)(t >= 3 ? 6144 : 0) * 512;
#pragma unroll
  for (int r = 0; r < 4; r++) {
    int grr = gr + r;
    int v = turn_row_map(grr, t);
    int urow = (grr >> 7) * 384 + tm3 * 128 + (grr & 127);
#pragma unroll
    for (int ct = 0; ct < 2; ct++) {
      float D = (ct == 0) ? acc0[r] : acc1[r];
      int c = (bx & 3) * 64 + ch * 32 + ct * 16 + nl;
      if (g == 0) {
        g1[(size_t)grr * 512 + c] = D + up[(size_t)urow * 512 + c];
      } else if (g == 1) {
        float rpre = D + up[(size_t)urow * 512 + 256 + c];
        float rv = 1.f / (1.f + __expf(-rpre));
        int hidx = v * 256 + c;
        float hv = reconf(hbh[hidx], hbl[hidx]);
        float rhv = rv * hv;
        unsigned short hh, ll; splitbf(rhv, hh, ll);
        rbh[grr * 256 + c] = hh; rbl[grr * 256 + c] = ll;
      } else {
        g1[(size_t)grr * 512 + 256 + c] = D + bn[c];
      }
    }
  }
}

// -------- GRU combine -> h planes; 256 blocks BK=64 (+8 out-zero blocks at t=5) ----
__global__ void __launch_bounds__(256)
k_mf3(const unsigned short* __restrict__ rbh, const unsigned short* __restrict__ rbl,
      const unsigned short* __restrict__ wth, const unsigned short* __restrict__ wtl,
      const float* __restrict__ g1,
      unsigned short* __restrict__ hbh, unsigned short* __restrict__ hbl,
      float* __restrict__ outp, int t) {
  __shared__ __align__(16) unsigned short Ah[32][72], Al[32][72];
  __shared__ __align__(16) unsigned short Bh[64][72], Bl[64][72];
  int l = blockIdx.x, tid = threadIdx.x;
  if (l >= 256) {  // out-zero blocks (only launched at t=5)
    ((float4*)outp)[(l - 256) * 256 + tid] = make_float4(0.f, 0.f, 0.f, 0.f);
    return;
  }
  int bx = (l & 31) >> 3, by = (l >> 5) * 8 + (l & 7);   // 4 x 64

  int ar = tid >> 3, aq = tid & 7;
  int bn_ = tid >> 2, bq = tid & 3;
  int gmA = by * 32 + ar;
  const unsigned short* ahp = rbh + (size_t)gmA * 256;
  const unsigned short* alp = rbl + (size_t)gmA * 256;
  int nbase = 1536 + bx * 64;              // Un
  const unsigned short* bhp = wth + (size_t)(nbase + bn_) * 256;
  const unsigned short* blp = wtl + (size_t)(nbase + bn_) * 256;

  int lane = tid & 63, wv = tid >> 6;
  int rh = wv >> 1, ch = wv & 1;
  int quad = lane >> 4, nl = lane & 15;
  f32x4 acc0 = {0.f, 0.f, 0.f, 0.f}, acc1 = {0.f, 0.f, 0.f, 0.f};
  gemm32x64_k64(ahp, alp, bhp, blp, Ah, Al, Bh, Bl, ar, aq, bn_, bq, rh, ch, quad, nl, acc0, acc1);

  int gr = by * 32 + rh * 16 + quad * 4;
#pragma unroll
  for (int r = 0; r < 4; r++) {
    int grr = gr + r;
    int v = turn_row_map(grr, t);
#pragma unroll
    for (int ct = 0; ct < 2; ct++) {
      float D = (ct == 0) ? acc0[r] : acc1[r];
      int c = bx * 64 + ch * 32 + ct * 16 + nl;
      float zpre = g1[(size_t)grr * 512 + c];
      float npre = g1[(size_t)grr * 512 + 256 + c] + D;
      float z = 1.f / (1.f + __expf(-zpre));
      float n = tanhf(npre);
      int hidx = v * 256 + c;
      float hv = reconf(hbh[hidx], hbl[hidx]);
      float hn = (1.f - z) * hv + z * n;
      unsigned short hh, ll; splitbf(hn, hh, ll);
      hbh[hidx] = hh;
      hbl[hidx] = ll;
    }
  }
}

// one block per (b,t): softmax over 128 node scores (wave-parallel), weighted mean of h
__global__ void __launch_bounds__(256)
k_pool(const float* __restrict__ score,
       const unsigned short* __restrict__ hbh,
       const unsigned short* __restrict__ hbl,
       float* __restrict__ out) {
  __shared__ float a[128];
  __shared__ float red[8];
  int bt = blockIdx.x;
  int base = bt * 128;
  int tid = threadIdx.x;
  float v = (tid < 128) ? score[base + tid] : -1e30f;
  float m = v;
#pragma unroll
  for (int s = 1; s < 64; s <<= 1) m = fmaxf(m, __shfl_xor(m, s));
  if ((tid & 63) == 0) red[tid >> 6] = m;
  __syncthreads();
  float mx = fmaxf(red[0], red[1]);
  float e = (tid < 128) ? __expf(v - mx) : 0.f;
  if (tid < 128) a[tid] = e;
  float s_ = e;
#pragma unroll
  for (int s = 1; s < 64; s <<= 1) s_ += __shfl_xor(s_, s);
  if ((tid & 63) == 0) red[4 + (tid >> 6)] = s_;
  __syncthreads();
  float sinv = 1.f / ((red[4] + red[5]) * 128.f);
  float acc = 0.f;
  for (int n = 0; n < 128; n++) {
    int idx = (base + n) * 256 + tid;
    acc += a[n] * reconf(hbh[idx], hbl[idx]);
  }
  int b = bt / 6, tt = bt % 6, spk = tt & 1;
  atomicAdd(&out[spk * 4096 + b * 256 + tid], acc * sinv);
}

extern "C" void kernel_launch(void* const* d_in, const int* in_sizes, int n_in,
                              void* d_out, int out_size, void* d_ws, size_t ws_size,
                              hipStream_t stream) {
  const float* emb    = (const float*)d_in[0];
  const float* nmask  = (const float*)d_in[1];
  const float* W      = (const float*)d_in[2];
  const float* a_src  = (const float*)d_in[3];
  const float* a_dst  = (const float*)d_in[4];
  const float* Wz     = (const float*)d_in[5];
  const float* Uz     = (const float*)d_in[6];
  const float* Wr     = (const float*)d_in[7];
  const float* Ur     = (const float*)d_in[8];
  const float* Wn     = (const float*)d_in[9];
  const float* Un     = (const float*)d_in[10];
  const float* bz     = (const float*)d_in[11];
  const float* br     = (const float*)d_in[12];
  const float* bn     = (const float*)d_in[13];
  const int* nodeidx  = (const int*)d_in[14];
  const int* esrc     = (const int*)d_in[15];
  const int* edst     = (const int*)d_in[16];
  float* out = (float*)d_out;

  char* ws = (char*)d_ws;
  size_t off = 0;
  auto carve = [&](size_t bytes) { char* p = ws + off; off += (bytes + 255) & ~(size_t)255; return p; };
  float* Wh     = (float*)carve((size_t)NTOT * 256 * 4);
  unsigned short* hbh = (unsigned short*)carve((size_t)NTOT * 256 * 2);
  unsigned short* hbl = (unsigned short*)carve((size_t)NTOT * 256 * 2);
  unsigned short* mbh = (unsigned short*)carve(2048 * 256 * 2);
  unsigned short* mbl = (unsigned short*)carve(2048 * 256 * 2);
  unsigned short* rbh = (unsigned short*)carve(2048 * 256 * 2);
  unsigned short* rbl = (unsigned short*)carve(2048 * 256 * 2);
  float* es     = (float*)carve(NTOT * 4 * 4);
  float* ed     = (float*)carve(NTOT * 4 * 4);
  float* g1     = (float*)carve(2048 * 512 * 4);
  float* uacc   = (float*)carve((size_t)12288 * 512 * 4);   // 2 banks: t<3 / t>=3
  float* score  = (float*)carve(NTOT * 4);
  int*   cnt    = (int*)carve(NTOT * 4);
  unsigned short* adj = (unsigned short*)carve((size_t)NTOT * MAXDEG * 2);
  unsigned short* wth = (unsigned short*)carve(1792 * 256 * 2);
  unsigned short* wtl = (unsigned short*)carve(1792 * 256 * 2);
  if (off > ws_size) return;  // fail cleanly if workspace too small

  hipMemsetAsync(cnt, 0, NTOT * 4, stream);
  k_prep<<<3952, 256, 0, stream>>>(emb, nmask, nodeidx, W, Wz, Wr, Wn, Uz, Ur, Un,
                                   esrc, edst, cnt, hbh, hbl, wth, wtl, adj);
  k_mf5<<<2304, 256, 0, stream>>>(hbh, hbl, wth, wtl, Wh, uacc, bz, br,
                                  a_src, a_dst, es, ed);

  for (int t = 0; t < 6; t++) {
    if (t > 0)
      k_upd<<<256, 256, 0, stream>>>(hbh, hbl, wth, wtl, Wh, a_src, a_dst, es, ed, t - 1);
    if (t < 5)
      k_attn<<<512, 256, 0, stream>>>(cnt, adj, es, ed, Wh, mbh, mbl, score, t, 0);
    else
      k_attn<<<3072, 256, 0, stream>>>(cnt, adj, es, ed, Wh, mbh, mbl, score, t, 1);
    k_mf2<<<768, 256, 0, stream>>>(mbh, mbl, wth, wtl, uacc, bn, hbh, hbl,
                                   g1, rbh, rbl, t);
    k_mf3<<<(t == 5 ? 264 : 256), 256, 0, stream>>>(rbh, rbl, wth, wtl, g1,
                                                    hbh, hbl, out, t);
  }

  k_pool<<<96, 256, 0, stream>>>(score, hbh, hbl, out);
}